// Round 1
// baseline (305.265 us; speedup 1.0000x reference)
//
#include <hip/hip_runtime.h>
#include <hip/hip_bf16.h>

#define BB 8
#define NN 1024
#define FIN 256
#define FOUT 64
#define NEGV (-9000000000000000.0f)

typedef __hip_bfloat16 bf16;
typedef short bf16x8 __attribute__((ext_vector_type(8)));
typedef float f32x4 __attribute__((ext_vector_type(4)));

__device__ __forceinline__ float b2f(bf16 v) { return __bfloat162float(v); }
__device__ __forceinline__ float bu2f(unsigned short u) {
  union { unsigned int i; float f; } c;
  c.i = ((unsigned int)u) << 16;
  return c.f;
}
__device__ __forceinline__ unsigned short f2bu(float v) {
  bf16 t = __float2bfloat16(v);
  return *(unsigned short*)&t;
}

// async global->LDS, 16B per lane; LDS dest is wave-uniform base (+lane*16 by HW)
__device__ __forceinline__ void gload_lds16(const unsigned short* g,
                                            unsigned short* l) {
  __builtin_amdgcn_global_load_lds(
      (__attribute__((address_space(1))) void*)(unsigned long long)(const void*)g,
      (__attribute__((address_space(3))) void*)l, 16, 0, 0);
}

__device__ __forceinline__ float waveRedSum(float v) {
  for (int d = 32; d; d >>= 1) v += __shfl_down(v, d);
  return v;
}
__device__ __forceinline__ float waveRedMax(float v) {
  for (int d = 32; d; d >>= 1) v = fmaxf(v, __shfl_down(v, d));
  return v;
}
__device__ __forceinline__ float waveRedMin(float v) {
  for (int d = 32; d; d >>= 1) v = fminf(v, __shfl_down(v, d));
  return v;
}

__device__ __forceinline__ float blockSumF(float v, float* tmp) {
  __syncthreads();
  v = waveRedSum(v);
  if ((threadIdx.x & 63) == 0) tmp[threadIdx.x >> 6] = v;
  __syncthreads();
  return tmp[0] + tmp[1] + tmp[2] + tmp[3];
}
__device__ __forceinline__ float blockMaxF(float v, float* tmp) {
  __syncthreads();
  v = waveRedMax(v);
  if ((threadIdx.x & 63) == 0) tmp[threadIdx.x >> 6] = v;
  __syncthreads();
  return fmaxf(fmaxf(tmp[0], tmp[1]), fmaxf(tmp[2], tmp[3]));
}
__device__ __forceinline__ float blockMinF(float v, float* tmp) {
  __syncthreads();
  v = waveRedMin(v);
  if ((threadIdx.x & 63) == 0) tmp[threadIdx.x >> 6] = v;
  __syncthreads();
  return fminf(fminf(tmp[0], tmp[1]), fminf(tmp[2], tmp[3]));
}

__global__ void k_fill(unsigned short* o, int n, unsigned short pat) {
  int i = blockIdx.x * blockDim.x + threadIdx.x;
  int stride = gridDim.x * blockDim.x;
  for (; i < n; i += stride) o[i] = pat;
}

// dtype probe
__global__ void k_detect(const unsigned short* xu, float* flag) {
  const int tid = threadIdx.x;
  float mx = 0.0f, zc = 0.0f;
  for (int i = tid; i < 8192; i += 256) {
    unsigned short u = xu[i];
    float v = bu2f(u);
    if (u == 0 || u == 0x8000) zc += 1.0f;
    mx = fmaxf(mx, fabsf(v));
  }
  __shared__ float tmp[4];
  float gm = blockMaxF(mx, tmp);
  float gz = blockSumF(zc, tmp);
  if (tid == 0) flag[0] = (gm > 1.0e6f || gz > 2048.0f) ? 1.0f : 0.0f;
}

// h = x @ W per (b,n) row; sq = |h|^2; wh1 = h.a1; wh2 = h.a2
__global__ void __launch_bounds__(64) k_h(const void* xv, const void* Wv,
                                          const void* av,
                                          const float* __restrict__ flag,
                                          float* __restrict__ h,
                                          float* __restrict__ sq,
                                          float* __restrict__ wh1,
                                          float* __restrict__ wh2) {
  const int bn = blockIdx.x;
  const int o = threadIdx.x;
  const bool f32m = (flag[0] != 0.0f);
  __shared__ float xs[FIN];
  if (f32m) {
    const float* xr = (const float*)xv + (size_t)bn * FIN;
    for (int i = o; i < FIN; i += 64) xs[i] = xr[i];
  } else {
    const bf16* xr = (const bf16*)xv + (size_t)bn * FIN;
    for (int i = o; i < FIN; i += 64) xs[i] = b2f(xr[i]);
  }
  __syncthreads();
  float acc = 0.f;
  if (f32m) {
    const float* Wf = (const float*)Wv;
    for (int i = 0; i < FIN; ++i) acc += xs[i] * Wf[i * FOUT + o];
  } else {
    const bf16* Wb = (const bf16*)Wv;
    for (int i = 0; i < FIN; ++i) acc += xs[i] * b2f(Wb[i * FOUT + o]);
  }
  h[(size_t)bn * FOUT + o] = acc;
  float a1, a2;
  if (f32m) {
    a1 = ((const float*)av)[o];
    a2 = ((const float*)av)[FOUT + o];
  } else {
    a1 = b2f(((const bf16*)av)[o]);
    a2 = b2f(((const bf16*)av)[FOUT + o]);
  }
  float s = waveRedSum(acc * acc);
  float w1 = waveRedSum(acc * a1);
  float w2 = waveRedSum(acc * a2);
  if (o == 0) {
    sq[bn] = s;
    wh1[bn] = w1;
    wh2[bn] = w2;
  }
}

// batched: M[z][n][m] = exp(-dist), exact 1.0 diag, written as hi/lo bf16 split
__global__ void __launch_bounds__(256) k_g(const float* __restrict__ h,
                                           const float* __restrict__ sq,
                                           unsigned short* __restrict__ Mh,
                                           unsigned short* __restrict__ Ml) {
  const int z = blockIdx.z;
  const float* hb = h + (size_t)z * NN * FOUT;
  const float* sqb = sq + (size_t)z * NN;
  unsigned short* mhb = Mh + (size_t)z * NN * NN;
  unsigned short* mlb = Ml + (size_t)z * NN * NN;
  const int tr = blockIdx.y * 64, tc = blockIdx.x * 64;
  __shared__ float Ah[64][68];
  __shared__ float Bh[64][68];
  const int tid = threadIdx.x;
  const int tx = tid & 15, ty = tid >> 4;
  for (int s = 0; s < 4; ++s) {
    int slot = tid + (s << 8);
    int r = slot >> 4;
    int c4 = (slot & 15) << 2;
    float4 va = *(const float4*)&hb[(size_t)(tr + r) * FOUT + c4];
    float4 vb = *(const float4*)&hb[(size_t)(tc + r) * FOUT + c4];
    Ah[r][c4] = va.x; Ah[r][c4 + 1] = va.y; Ah[r][c4 + 2] = va.z; Ah[r][c4 + 3] = va.w;
    Bh[r][c4] = vb.x; Bh[r][c4 + 1] = vb.y; Bh[r][c4 + 2] = vb.z; Bh[r][c4 + 3] = vb.w;
  }
  __syncthreads();
  float acc[4][4] = {};
  for (int k = 0; k < 64; ++k) {
    float ra[4], rb[4];
    for (int i = 0; i < 4; ++i) ra[i] = Ah[ty * 4 + i][k];
    for (int j = 0; j < 4; ++j) rb[j] = Bh[tx * 4 + j][k];
    for (int i = 0; i < 4; ++i)
      for (int j = 0; j < 4; ++j) acc[i][j] += ra[i] * rb[j];
  }
  for (int i = 0; i < 4; ++i) {
    int n = tr + ty * 4 + i;
    float sn = sqb[n];
    unsigned short hs[4], ls[4];
    for (int j = 0; j < 4; ++j) {
      int m = tc + tx * 4 + j;
      float d2 = sn + sqb[m] - 2.0f * acc[i][j];
      float v = (n == m) ? 1.0f : ((d2 > 0.0f) ? expf(-sqrtf(d2)) : 1.0f);
      hs[j] = f2bu(v);
      ls[j] = f2bu(v - bu2f(hs[j]));
    }
    ushort4 h4, l4;
    h4.x = hs[0]; h4.y = hs[1]; h4.z = hs[2]; h4.w = hs[3];
    l4.x = ls[0]; l4.y = ls[1]; l4.z = ls[2]; l4.w = ls[3];
    *(ushort4*)&mhb[(size_t)n * NN + tc + tx * 4] = h4;
    *(ushort4*)&mlb[(size_t)n * NN + tc + tx * 4] = l4;
  }
}

// invd[b][n] = 1 / max(rowsum(M), 1e-12)
__global__ void __launch_bounds__(256) k_invd(const unsigned short* __restrict__ Mh,
                                              const unsigned short* __restrict__ Ml,
                                              float* __restrict__ invd) {
  const int bn = blockIdx.x;
  const unsigned short* mh = Mh + (size_t)bn * NN;
  const unsigned short* ml = Ml + (size_t)bn * NN;
  const int tid = threadIdx.x;
  ushort4 h4 = *(const ushort4*)&mh[tid << 2];
  ushort4 l4 = *(const ushort4*)&ml[tid << 2];
  float s = (bu2f(h4.x) + bu2f(l4.x)) + (bu2f(h4.y) + bu2f(l4.y)) +
            (bu2f(h4.z) + bu2f(l4.z)) + (bu2f(h4.w) + bu2f(l4.w));
  __shared__ float tmp[4];
  float tot = blockSumF(s, tmp);
  if (tid == 0) invd[bn] = 1.0f / fmaxf(tot, 1e-12f);
}

// AT = M * D^-1 (column scale), split hi/lo. No transpose needed (M symmetric).
__global__ void __launch_bounds__(256) k_at(const unsigned short* __restrict__ Mh,
                                            const unsigned short* __restrict__ Ml,
                                            const float* __restrict__ invd,
                                            unsigned short* __restrict__ ATh,
                                            unsigned short* __restrict__ ATl) {
  const int bn = blockIdx.x;
  const int b = bn >> 10;
  const unsigned short* mh = Mh + (size_t)bn * NN;
  const unsigned short* ml = Ml + (size_t)bn * NN;
  const float* idv = invd + (b << 10);
  unsigned short* ah = ATh + (size_t)bn * NN;
  unsigned short* al = ATl + (size_t)bn * NN;
  const int c0 = threadIdx.x << 2;
  ushort4 h4 = *(const ushort4*)&mh[c0];
  ushort4 l4 = *(const ushort4*)&ml[c0];
  float4 iv = *(const float4*)&idv[c0];
  float v[4];
  v[0] = (bu2f(h4.x) + bu2f(l4.x)) * iv.x;
  v[1] = (bu2f(h4.y) + bu2f(l4.y)) * iv.y;
  v[2] = (bu2f(h4.z) + bu2f(l4.z)) * iv.z;
  v[3] = (bu2f(h4.w) + bu2f(l4.w)) * iv.w;
  unsigned short hs[4], ls[4];
  for (int k = 0; k < 4; ++k) {
    hs[k] = f2bu(v[k]);
    ls[k] = f2bu(v[k] - bu2f(hs[k]));
  }
  ushort4 oh, ol;
  oh.x = hs[0]; oh.y = hs[1]; oh.z = hs[2]; oh.w = hs[3];
  ol.x = ls[0]; ol.y = ls[1]; ol.z = ls[2]; ol.w = ls[3];
  *(ushort4*)&ah[c0] = oh;
  *(ushort4*)&al[c0] = ol;
}

// MFMA GEMM1: U = M * (M D^-1)  (split bf16, 2-phase dbuf BK=32 pipeline).
// U is symmetric, so the transposed epilogue write lands U in straight layout.
__global__ void __launch_bounds__(256) k_mm1(
    const unsigned short* __restrict__ Ain_h, const unsigned short* __restrict__ Ain_l,
    const unsigned short* __restrict__ Bin_h, const unsigned short* __restrict__ Bin_l,
    unsigned short* __restrict__ Uh, unsigned short* __restrict__ Ul) {
  const int bid = blockIdx.x;
  const int z = bid & 7;
  const int t6 = bid >> 3;
  const int tr = (t6 >> 3) * 128, tc = (t6 & 7) * 128;
  const size_t MAT = (size_t)NN * NN;
  __shared__ unsigned short sm[32768];  // [2 buf][4 mat][128*32]
  const int tid = threadIdx.x;
  const int wave = tid >> 6, lane = tid & 63;
  const int wm = (wave >> 1) * 64, wn = (wave & 1) * 64;
  const int q = lane >> 4, ln = lane & 15;
  // staging geometry: 8 issues x (16 rows x 64B); lane -> (row16=lane>>2, slot=lane&3)
  const int srow = lane >> 2;
  const int scol = ((lane & 3) ^ ((srow >> 1) & 3)) << 3;  // pre-swizzled global src
  const unsigned short* gp0;
  if (wave == 0)      gp0 = Ain_h + z * MAT + (size_t)tr * NN;
  else if (wave == 1) gp0 = Ain_l + z * MAT + (size_t)tr * NN;
  else if (wave == 2) gp0 = Bin_h + z * MAT + (size_t)tc * NN;
  else                gp0 = Bin_l + z * MAT + (size_t)tc * NN;
  f32x4 acc[4][4];
  for (int i = 0; i < 4; ++i)
    for (int j = 0; j < 4; ++j) acc[i][j] = (f32x4){0.f, 0.f, 0.f, 0.f};
  const int rxor = (ln >> 1) & 3;
  const int fcol = (q ^ rxor) << 3;  // frag read slot (undoes store swizzle)
  // prologue: stage chunk 0 into buf 0
  {
    unsigned short* lb = &sm[wave << 12];
    for (int t = 0; t < 8; ++t)
      gload_lds16(gp0 + (size_t)(t * 16 + srow) * NN + scol, lb + t * 512);
  }
  __syncthreads();  // drains vmcnt(0)
  for (int ch = 0; ch < 32; ++ch) {
    const int cur = (ch & 1) << 14;
    if (ch < 31) {
      const unsigned short* gpk = gp0 + (ch + 1) * 32 + scol;
      unsigned short* lb = &sm[(((ch + 1) & 1) << 14) + (wave << 12)];
      for (int t = 0; t < 8; ++t)
        gload_lds16(gpk + (size_t)(t * 16 + srow) * NN, lb + t * 512);
    }
    bf16x8 fah[4], fal[4], fbh[4], fbl[4];
    for (int i = 0; i < 4; ++i) {
      int off = cur + (wm + i * 16 + ln) * 32 + fcol;
      fah[i] = *(const bf16x8*)&sm[off];
      fal[i] = *(const bf16x8*)&sm[off + 4096];
    }
    for (int j = 0; j < 4; ++j) {
      int off = cur + (wn + j * 16 + ln) * 32 + fcol;
      fbh[j] = *(const bf16x8*)&sm[off + 8192];
      fbl[j] = *(const bf16x8*)&sm[off + 12288];
    }
    for (int i = 0; i < 4; ++i)
      for (int j = 0; j < 4; ++j) {
        acc[i][j] = __builtin_amdgcn_mfma_f32_16x16x32_bf16(fah[i], fbh[j], acc[i][j], 0, 0, 0);
        acc[i][j] = __builtin_amdgcn_mfma_f32_16x16x32_bf16(fah[i], fbl[j], acc[i][j], 0, 0, 0);
        acc[i][j] = __builtin_amdgcn_mfma_f32_16x16x32_bf16(fal[i], fbh[j], acc[i][j], 0, 0, 0);
      }
    __syncthreads();  // implicit vmcnt(0)+lgkmcnt(0) drain AFTER compute
  }
  unsigned short* cth = Uh + z * MAT;
  unsigned short* ctl = Ul + z * MAT;
  for (int i = 0; i < 4; ++i) {
    int m0 = tr + wm + i * 16 + q * 4;
    for (int j = 0; j < 4; ++j) {
      int n = tc + wn + j * 16 + ln;
      ushort4 h4, l4;
      unsigned short hs[4], ls[4];
      for (int reg = 0; reg < 4; ++reg) {
        float v = acc[i][j][reg];
        hs[reg] = f2bu(v);
        ls[reg] = f2bu(v - bu2f(hs[reg]));
      }
      h4.x = hs[0]; h4.y = hs[1]; h4.z = hs[2]; h4.w = hs[3];
      l4.x = ls[0]; l4.y = ls[1]; l4.z = ls[2]; l4.w = ls[3];
      *(ushort4*)&cth[(size_t)n * NN + m0] = h4;
      *(ushort4*)&ctl[(size_t)n * NN + m0] = l4;
    }
  }
}

// MFMA GEMM2: V = U * (M D^-1) (split bf16, same pipeline), raw f32 out.
__global__ void __launch_bounds__(256) k_mm2(
    const unsigned short* __restrict__ Ain_h, const unsigned short* __restrict__ Ain_l,
    const unsigned short* __restrict__ Bin_h, const unsigned short* __restrict__ Bin_l,
    float* __restrict__ S) {
  const int bid = blockIdx.x;
  const int z = bid & 7;
  const int t6 = bid >> 3;
  const int tr = (t6 >> 3) * 128, tc = (t6 & 7) * 128;
  const size_t MAT = (size_t)NN * NN;
  __shared__ unsigned short sm[32768];
  const int tid = threadIdx.x;
  const int wave = tid >> 6, lane = tid & 63;
  const int wm = (wave >> 1) * 64, wn = (wave & 1) * 64;
  const int q = lane >> 4, ln = lane & 15;
  const int srow = lane >> 2;
  const int scol = ((lane & 3) ^ ((srow >> 1) & 3)) << 3;
  const unsigned short* gp0;
  if (wave == 0)      gp0 = Ain_h + z * MAT + (size_t)tr * NN;
  else if (wave == 1) gp0 = Ain_l + z * MAT + (size_t)tr * NN;
  else if (wave == 2) gp0 = Bin_h + z * MAT + (size_t)tc * NN;
  else                gp0 = Bin_l + z * MAT + (size_t)tc * NN;
  f32x4 acc[4][4];
  for (int i = 0; i < 4; ++i)
    for (int j = 0; j < 4; ++j) acc[i][j] = (f32x4){0.f, 0.f, 0.f, 0.f};
  const int rxor = (ln >> 1) & 3;
  const int fcol = (q ^ rxor) << 3;
  {
    unsigned short* lb = &sm[wave << 12];
    for (int t = 0; t < 8; ++t)
      gload_lds16(gp0 + (size_t)(t * 16 + srow) * NN + scol, lb + t * 512);
  }
  __syncthreads();
  for (int ch = 0; ch < 32; ++ch) {
    const int cur = (ch & 1) << 14;
    if (ch < 31) {
      const unsigned short* gpk = gp0 + (ch + 1) * 32 + scol;
      unsigned short* lb = &sm[(((ch + 1) & 1) << 14) + (wave << 12)];
      for (int t = 0; t < 8; ++t)
        gload_lds16(gpk + (size_t)(t * 16 + srow) * NN, lb + t * 512);
    }
    bf16x8 fah[4], fal[4], fbh[4], fbl[4];
    for (int i = 0; i < 4; ++i) {
      int off = cur + (wm + i * 16 + ln) * 32 + fcol;
      fah[i] = *(const bf16x8*)&sm[off];
      fal[i] = *(const bf16x8*)&sm[off + 4096];
    }
    for (int j = 0; j < 4; ++j) {
      int off = cur + (wn + j * 16 + ln) * 32 + fcol;
      fbh[j] = *(const bf16x8*)&sm[off + 8192];
      fbl[j] = *(const bf16x8*)&sm[off + 12288];
    }
    for (int i = 0; i < 4; ++i)
      for (int j = 0; j < 4; ++j) {
        acc[i][j] = __builtin_amdgcn_mfma_f32_16x16x32_bf16(fah[i], fbh[j], acc[i][j], 0, 0, 0);
        acc[i][j] = __builtin_amdgcn_mfma_f32_16x16x32_bf16(fah[i], fbl[j], acc[i][j], 0, 0, 0);
        acc[i][j] = __builtin_amdgcn_mfma_f32_16x16x32_bf16(fal[i], fbh[j], acc[i][j], 0, 0, 0);
      }
    __syncthreads();
  }
  float* Sb = S + z * MAT;
  for (int i = 0; i < 4; ++i) {
    int m0 = tr + wm + i * 16 + q * 4;
    for (int j = 0; j < 4; ++j) {
      int n = tc + wn + j * 16 + ln;
      for (int reg = 0; reg < 4; ++reg)
        Sb[(size_t)(m0 + reg) * NN + n] = acc[i][j][reg];
    }
  }
}

// combine using symmetry: S[i][j] = 0.5*(invd_i+invd_j)*(M + 0.8U + 0.64V)[i][j]
// upper pair-tiles only; single-orientation reads; writes S[i1] and S[i2]^T.
__global__ void __launch_bounds__(256) k_comb(
    const unsigned short* __restrict__ Mh, const unsigned short* __restrict__ Ml,
    const unsigned short* __restrict__ Uh, const unsigned short* __restrict__ Ul,
    const float* __restrict__ invd, float* __restrict__ S) {
  const int z = blockIdx.y;
  const size_t base = (size_t)z * NN * NN;
  int p = blockIdx.x;  // 0..527 -> (ti<=tj)
  int ti = 0, rem = p;
  while (rem >= 32 - ti) {
    rem -= 32 - ti;
    ++ti;
  }
  const int tj = ti + rem;
  const int tid = threadIdx.x;
  const int r = tid >> 3;          // 0..31
  const int c0 = (tid & 7) << 2;   // 0..28
  __shared__ float T[32][33];
  const size_t i1 = base + (size_t)(ti * 32 + r) * NN + tj * 32 + c0;
  float4 v3 = *(const float4*)&S[i1];  // V values
  ushort4 m4h = *(const ushort4*)&Mh[i1];
  ushort4 m4l = *(const ushort4*)&Ml[i1];
  ushort4 u4h = *(const ushort4*)&Uh[i1];
  ushort4 u4l = *(const ushort4*)&Ul[i1];
  const float idr = invd[(z << 10) + ti * 32 + r];
  float4 idc = *(const float4*)&invd[(z << 10) + tj * 32 + c0];
  float v[4];
  v[0] = 0.5f * (idr + idc.x) *
         ((bu2f(m4h.x) + bu2f(m4l.x)) + 0.8f * (bu2f(u4h.x) + bu2f(u4l.x)) + 0.64f * v3.x);
  v[1] = 0.5f * (idr + idc.y) *
         ((bu2f(m4h.y) + bu2f(m4l.y)) + 0.8f * (bu2f(u4h.y) + bu2f(u4l.y)) + 0.64f * v3.y);
  v[2] = 0.5f * (idr + idc.z) *
         ((bu2f(m4h.z) + bu2f(m4l.z)) + 0.8f * (bu2f(u4h.z) + bu2f(u4l.z)) + 0.64f * v3.z);
  v[3] = 0.5f * (idr + idc.w) *
         ((bu2f(m4h.w) + bu2f(m4l.w)) + 0.8f * (bu2f(u4h.w) + bu2f(u4l.w)) + 0.64f * v3.w);
  *(float4*)&S[i1] = make_float4(v[0], v[1], v[2], v[3]);
  T[r][c0] = v[0]; T[r][c0 + 1] = v[1]; T[r][c0 + 2] = v[2]; T[r][c0 + 3] = v[3];
  __syncthreads();
  const size_t i2 = base + (size_t)(tj * 32 + r) * NN + ti * 32 + c0;
  *(float4*)&S[i2] = make_float4(T[c0][r], T[c0 + 1][r], T[c0 + 2][r],
                                 T[c0 + 3][r]);
}

// thr[b] = min(diag) - mean(diag[:-1] - offdiag)
__global__ void __launch_bounds__(256) k_thr(const float* __restrict__ S,
                                             float* __restrict__ thr) {
  const int b = blockIdx.x;
  const float* Sb = S + (size_t)b * NN * NN;
  const int tid = threadIdx.x;
  float mn = 3.0e38f;
  float rsum = 0.f;
  for (int n = tid; n < NN; n += 256) {
    float d = Sb[(size_t)n * NN + n];
    mn = fminf(mn, d);
    if (n < NN - 1) rsum += d - Sb[(size_t)n * NN + n + 1];
  }
  __shared__ float tmp[4];
  float mtot = blockMinF(mn, tmp);
  float stot = blockSumF(rsum, tmp);
  if (tid == 0) thr[b] = mtot - stot / 1023.0f;
}

__global__ void __launch_bounds__(256) k_stats(const float* __restrict__ S,
                                               const float* __restrict__ thr,
                                               const float* __restrict__ wh1,
                                               const float* __restrict__ wh2,
                                               float* __restrict__ meanv,
                                               float* __restrict__ rstdv) {
  const int n = blockIdx.x;
  const int tid = threadIdx.x;
  double s1 = 0.0, s2 = 0.0;
  for (int b = 0; b < BB; ++b) {
    float t = thr[b];
    float w1 = wh1[b * NN + n];
    const float* Srow = S + ((size_t)b * NN + n) * NN;
    const float* w2p = wh2 + b * NN;
    for (int m = tid; m < NN; m += 256) {
      float e = w1 + w2p[m];
      e = (e > 0.f) ? e : 0.01f * e;
      float att = (Srow[m] > t) ? e : NEGV;
      s1 += (double)att;
      s2 += (double)att * (double)att;
    }
  }
  __shared__ double red[256];
  red[tid] = s1;
  __syncthreads();
  for (int s = 128; s > 0; s >>= 1) {
    if (tid < s) red[tid] += red[tid + s];
    __syncthreads();
  }
  double t1 = red[0];
  __syncthreads();
  red[tid] = s2;
  __syncthreads();
  for (int s = 128; s > 0; s >>= 1) {
    if (tid < s) red[tid] += red[tid + s];
    __syncthreads();
  }
  double t2 = red[0];
  if (tid == 0) {
    double mean = t1 / 8192.0;
    double var = t2 / 8192.0 - mean * mean;
    if (var < 0.0) var = 0.0;
    meanv[n] = (float)mean;
    rstdv[n] = (float)(1.0 / sqrt(var + 1e-5));
  }
}

__global__ void __launch_bounds__(256) k_out(const float* __restrict__ S,
                                             const float* __restrict__ thr,
                                             const float* __restrict__ wh1,
                                             const float* __restrict__ wh2,
                                             const float* __restrict__ meanv,
                                             const float* __restrict__ rstdv,
                                             const float* __restrict__ flag,
                                             void* outv) {
  const int bn = blockIdx.x;
  const int b = bn >> 10;
  const int n = bn & 1023;
  const int tid = threadIdx.x;
  const bool f32m = (flag[0] != 0.0f);
  const float t = thr[b];
  const float w1 = wh1[bn];
  const float* Srow = S + (size_t)bn * NN;
  const float* w2p = wh2 + b * NN;
  float v[4];
  float mx = -3.0e38f;
  for (int w = 0; w < 4; ++w) {
    int m = tid + (w << 8);
    float e = w1 + w2p[m];
    e = (e > 0.f) ? e : 0.01f * e;
    float att = (Srow[m] > t) ? e : NEGV;
    float vv = (att - meanv[n]) * rstdv[n];
    v[w] = vv;
    mx = fmaxf(mx, vv);
  }
  __shared__ float tmp[4];
  float gmx = blockMaxF(mx, tmp);
  float sum = 0.f;
  for (int w = 0; w < 4; ++w) {
    v[w] = __expf(v[w] - gmx);
    sum += v[w];
  }
  float gsum = blockSumF(sum, tmp);
  for (int w = 0; w < 4; ++w) {
    int m = tid + (w << 8);
    float val = v[w] / gsum;
    if (f32m) {
      ((float*)outv)[(size_t)bn * NN + m] = val;
    } else {
      ((bf16*)outv)[(size_t)bn * NN + m] = __float2bfloat16(val);
    }
  }
}

extern "C" void kernel_launch(void* const* d_in, const int* in_sizes, int n_in,
                              void* d_out, int out_size, void* d_ws,
                              size_t ws_size, hipStream_t stream) {
  float* ws = (float*)d_ws;

  float* sq = ws;              // 8192
  float* wh1 = ws + 8192;      // 8192
  float* wh2 = ws + 16384;     // 8192
  float* thr = ws + 24576;     // 8
  float* meanv = ws + 24608;   // 1024
  float* rstdv = ws + 25632;   // 1024
  float* flag = ws + 26656;    // 8
  float* invd = ws + 26664;    // 8192
  float* h = ws + 65536;       // 524288

  unsigned short* Mh = (unsigned short*)(ws + 589824);
  unsigned short* Ml = (unsigned short*)(ws + 4784128);
  unsigned short* ATh = (unsigned short*)(ws + 8978432);
  unsigned short* ATl = (unsigned short*)(ws + 13172736);
  unsigned short* Uh = (unsigned short*)(ws + 17367040);
  unsigned short* Ul = (unsigned short*)(ws + 21561344);
  float* Sf = ws + 25755648;  // 8388608 floats (V -> S)
  const size_t needed_fast = (25755648ull + 8388608ull) * 4ull;

  if (ws_size < needed_fast) {
    k_fill<<<dim3(2048), 256, 0, stream>>>((unsigned short*)d_out, out_size,
                                           (unsigned short)0xBF80);
    return;
  }

  k_detect<<<dim3(1), 256, 0, stream>>>((const unsigned short*)d_in[0], flag);
  k_h<<<dim3(BB * NN), 64, 0, stream>>>(d_in[0], d_in[1], d_in[2], flag, h, sq,
                                        wh1, wh2);
  k_g<<<dim3(16, 16, BB), 256, 0, stream>>>(h, sq, Mh, Ml);
  k_invd<<<dim3(BB * NN), 256, 0, stream>>>(Mh, Ml, invd);
  k_at<<<dim3(BB * NN), 256, 0, stream>>>(Mh, Ml, invd, ATh, ATl);
  k_mm1<<<dim3(512), 256, 0, stream>>>(Mh, Ml, ATh, ATl, Uh, Ul);
  k_mm2<<<dim3(512), 256, 0, stream>>>(Uh, Ul, ATh, ATl, Sf);
  k_comb<<<dim3(528, BB), 256, 0, stream>>>(Mh, Ml, Uh, Ul, invd, Sf);
  k_thr<<<dim3(BB), 256, 0, stream>>>(Sf, thr);
  k_stats<<<dim3(NN), 256, 0, stream>>>(Sf, thr, wh1, wh2, meanv, rstdv);
  k_out<<<dim3(BB * NN), 256, 0, stream>>>(Sf, thr, wh1, wh2, meanv, rstdv,
                                           flag, d_out);
}

// Round 2
// 262.256 us; speedup vs baseline: 1.1640x; 1.1640x over previous
//
#include <hip/hip_runtime.h>
#include <hip/hip_bf16.h>

#define BB 8
#define NN 1024
#define FIN 256
#define FOUT 64
#define NEGV (-9000000000000000.0f)

typedef __hip_bfloat16 bf16;
typedef short bf16x8 __attribute__((ext_vector_type(8)));
typedef float f32x4 __attribute__((ext_vector_type(4)));

__device__ __forceinline__ float b2f(bf16 v) { return __bfloat162float(v); }
__device__ __forceinline__ float bu2f(unsigned short u) {
  union { unsigned int i; float f; } c;
  c.i = ((unsigned int)u) << 16;
  return c.f;
}
__device__ __forceinline__ unsigned short f2bu(float v) {
  bf16 t = __float2bfloat16(v);
  return *(unsigned short*)&t;
}

// async global->LDS, 16B per lane; LDS dest is wave-uniform base (+lane*16 by HW)
__device__ __forceinline__ void gload_lds16(const unsigned short* g,
                                            unsigned short* l) {
  __builtin_amdgcn_global_load_lds(
      (__attribute__((address_space(1))) void*)(unsigned long long)(const void*)g,
      (__attribute__((address_space(3))) void*)l, 16, 0, 0);
}

__device__ __forceinline__ float waveRedSum(float v) {
  for (int d = 32; d; d >>= 1) v += __shfl_down(v, d);
  return v;
}
__device__ __forceinline__ float waveRedMax(float v) {
  for (int d = 32; d; d >>= 1) v = fmaxf(v, __shfl_down(v, d));
  return v;
}
__device__ __forceinline__ float waveRedMin(float v) {
  for (int d = 32; d; d >>= 1) v = fminf(v, __shfl_down(v, d));
  return v;
}

__device__ __forceinline__ float blockSumF(float v, float* tmp) {
  __syncthreads();
  v = waveRedSum(v);
  if ((threadIdx.x & 63) == 0) tmp[threadIdx.x >> 6] = v;
  __syncthreads();
  return tmp[0] + tmp[1] + tmp[2] + tmp[3];
}
__device__ __forceinline__ float blockMaxF(float v, float* tmp) {
  __syncthreads();
  v = waveRedMax(v);
  if ((threadIdx.x & 63) == 0) tmp[threadIdx.x >> 6] = v;
  __syncthreads();
  return fmaxf(fmaxf(tmp[0], tmp[1]), fmaxf(tmp[2], tmp[3]));
}
__device__ __forceinline__ float blockMinF(float v, float* tmp) {
  __syncthreads();
  v = waveRedMin(v);
  if ((threadIdx.x & 63) == 0) tmp[threadIdx.x >> 6] = v;
  __syncthreads();
  return fminf(fminf(tmp[0], tmp[1]), fminf(tmp[2], tmp[3]));
}

__global__ void k_fill(unsigned short* o, int n, unsigned short pat) {
  int i = blockIdx.x * blockDim.x + threadIdx.x;
  int stride = gridDim.x * blockDim.x;
  for (; i < n; i += stride) o[i] = pat;
}

__global__ void k_zero(float* p, int n) {
  int i = blockIdx.x * blockDim.x + threadIdx.x;
  if (i < n) p[i] = 0.f;
}

// dtype probe
__global__ void k_detect(const unsigned short* xu, float* flag) {
  const int tid = threadIdx.x;
  float mx = 0.0f, zc = 0.0f;
  for (int i = tid; i < 8192; i += 256) {
    unsigned short u = xu[i];
    float v = bu2f(u);
    if (u == 0 || u == 0x8000) zc += 1.0f;
    mx = fmaxf(mx, fabsf(v));
  }
  __shared__ float tmp[4];
  float gm = blockMaxF(mx, tmp);
  float gz = blockSumF(zc, tmp);
  if (tid == 0) flag[0] = (gm > 1.0e6f || gz > 2048.0f) ? 1.0f : 0.0f;
}

// h = x @ W per (b,n) row; sq = |h|^2; wh1 = h.a1; wh2 = h.a2
__global__ void __launch_bounds__(64) k_h(const void* xv, const void* Wv,
                                          const void* av,
                                          const float* __restrict__ flag,
                                          float* __restrict__ h,
                                          float* __restrict__ sq,
                                          float* __restrict__ wh1,
                                          float* __restrict__ wh2) {
  const int bn = blockIdx.x;
  const int o = threadIdx.x;
  const bool f32m = (flag[0] != 0.0f);
  __shared__ float xs[FIN];
  if (f32m) {
    const float* xr = (const float*)xv + (size_t)bn * FIN;
    for (int i = o; i < FIN; i += 64) xs[i] = xr[i];
  } else {
    const bf16* xr = (const bf16*)xv + (size_t)bn * FIN;
    for (int i = o; i < FIN; i += 64) xs[i] = b2f(xr[i]);
  }
  __syncthreads();
  float acc = 0.f;
  if (f32m) {
    const float* Wf = (const float*)Wv;
    for (int i = 0; i < FIN; ++i) acc += xs[i] * Wf[i * FOUT + o];
  } else {
    const bf16* Wb = (const bf16*)Wv;
    for (int i = 0; i < FIN; ++i) acc += xs[i] * b2f(Wb[i * FOUT + o]);
  }
  h[(size_t)bn * FOUT + o] = acc;
  float a1, a2;
  if (f32m) {
    a1 = ((const float*)av)[o];
    a2 = ((const float*)av)[FOUT + o];
  } else {
    a1 = b2f(((const bf16*)av)[o]);
    a2 = b2f(((const bf16*)av)[FOUT + o]);
  }
  float s = waveRedSum(acc * acc);
  float w1 = waveRedSum(acc * a1);
  float w2 = waveRedSum(acc * a2);
  if (o == 0) {
    sq[bn] = s;
    wh1[bn] = w1;
    wh2[bn] = w2;
  }
}

// batched: M[z][n][m] = exp(-dist), exact 1.0 diag, written as hi/lo bf16 split.
// Also accumulates exact-f32 row sums into rsum via one atomicAdd per row-tile.
__global__ void __launch_bounds__(256) k_g(const float* __restrict__ h,
                                           const float* __restrict__ sq,
                                           unsigned short* __restrict__ Mh,
                                           unsigned short* __restrict__ Ml,
                                           float* __restrict__ rsum) {
  const int z = blockIdx.z;
  const float* hb = h + (size_t)z * NN * FOUT;
  const float* sqb = sq + (size_t)z * NN;
  unsigned short* mhb = Mh + (size_t)z * NN * NN;
  unsigned short* mlb = Ml + (size_t)z * NN * NN;
  float* rsb = rsum + (size_t)z * NN;
  const int tr = blockIdx.y * 64, tc = blockIdx.x * 64;
  __shared__ float Ah[64][68];
  __shared__ float Bh[64][68];
  const int tid = threadIdx.x;
  const int tx = tid & 15, ty = tid >> 4;
  for (int s = 0; s < 4; ++s) {
    int slot = tid + (s << 8);
    int r = slot >> 4;
    int c4 = (slot & 15) << 2;
    float4 va = *(const float4*)&hb[(size_t)(tr + r) * FOUT + c4];
    float4 vb = *(const float4*)&hb[(size_t)(tc + r) * FOUT + c4];
    Ah[r][c4] = va.x; Ah[r][c4 + 1] = va.y; Ah[r][c4 + 2] = va.z; Ah[r][c4 + 3] = va.w;
    Bh[r][c4] = vb.x; Bh[r][c4 + 1] = vb.y; Bh[r][c4 + 2] = vb.z; Bh[r][c4 + 3] = vb.w;
  }
  __syncthreads();
  float acc[4][4] = {};
  for (int k = 0; k < 64; ++k) {
    float ra[4], rb[4];
    for (int i = 0; i < 4; ++i) ra[i] = Ah[ty * 4 + i][k];
    for (int j = 0; j < 4; ++j) rb[j] = Bh[tx * 4 + j][k];
    for (int i = 0; i < 4; ++i)
      for (int j = 0; j < 4; ++j) acc[i][j] += ra[i] * rb[j];
  }
  for (int i = 0; i < 4; ++i) {
    int n = tr + ty * 4 + i;
    float sn = sqb[n];
    unsigned short hs[4], ls[4];
    float vals[4];
    for (int j = 0; j < 4; ++j) {
      int m = tc + tx * 4 + j;
      float d2 = sn + sqb[m] - 2.0f * acc[i][j];
      float v = (n == m) ? 1.0f : ((d2 > 0.0f) ? expf(-sqrtf(d2)) : 1.0f);
      vals[j] = v;
      hs[j] = f2bu(v);
      ls[j] = f2bu(v - bu2f(hs[j]));
    }
    ushort4 h4, l4;
    h4.x = hs[0]; h4.y = hs[1]; h4.z = hs[2]; h4.w = hs[3];
    l4.x = ls[0]; l4.y = ls[1]; l4.z = ls[2]; l4.w = ls[3];
    *(ushort4*)&mhb[(size_t)n * NN + tc + tx * 4] = h4;
    *(ushort4*)&mlb[(size_t)n * NN + tc + tx * 4] = l4;
    // row-partial sum over this block's 64 columns -> one atomic per row
    float rs = (vals[0] + vals[1]) + (vals[2] + vals[3]);
    for (int d = 1; d < 16; d <<= 1) rs += __shfl_xor(rs, d);
    if (tx == 0) atomicAdd(&rsb[n], rs);
  }
}

// invd[i] = 1 / max(rsum[i], 1e-12)
__global__ void __launch_bounds__(256) k_recip(const float* __restrict__ rsum,
                                               float* __restrict__ invd) {
  int i = blockIdx.x * blockDim.x + threadIdx.x;
  if (i < BB * NN) invd[i] = 1.0f / fmaxf(rsum[i], 1e-12f);
}

// AT = M * D^-1 (column scale), split hi/lo. No transpose needed (M symmetric).
__global__ void __launch_bounds__(256) k_at(const unsigned short* __restrict__ Mh,
                                            const unsigned short* __restrict__ Ml,
                                            const float* __restrict__ invd,
                                            unsigned short* __restrict__ ATh,
                                            unsigned short* __restrict__ ATl) {
  const int bn = blockIdx.x;
  const int b = bn >> 10;
  const unsigned short* mh = Mh + (size_t)bn * NN;
  const unsigned short* ml = Ml + (size_t)bn * NN;
  const float* idv = invd + (b << 10);
  unsigned short* ah = ATh + (size_t)bn * NN;
  unsigned short* al = ATl + (size_t)bn * NN;
  const int c0 = threadIdx.x << 2;
  ushort4 h4 = *(const ushort4*)&mh[c0];
  ushort4 l4 = *(const ushort4*)&ml[c0];
  float4 iv = *(const float4*)&idv[c0];
  float v[4];
  v[0] = (bu2f(h4.x) + bu2f(l4.x)) * iv.x;
  v[1] = (bu2f(h4.y) + bu2f(l4.y)) * iv.y;
  v[2] = (bu2f(h4.z) + bu2f(l4.z)) * iv.z;
  v[3] = (bu2f(h4.w) + bu2f(l4.w)) * iv.w;
  unsigned short hs[4], ls[4];
  for (int k = 0; k < 4; ++k) {
    hs[k] = f2bu(v[k]);
    ls[k] = f2bu(v[k] - bu2f(hs[k]));
  }
  ushort4 oh, ol;
  oh.x = hs[0]; oh.y = hs[1]; oh.z = hs[2]; oh.w = hs[3];
  ol.x = ls[0]; ol.y = ls[1]; ol.z = ls[2]; ol.w = ls[3];
  *(ushort4*)&ah[c0] = oh;
  *(ushort4*)&al[c0] = ol;
}

// MFMA GEMM1: U = M * (M D^-1)^T = M D^-1 M (split bf16, proven 2-barrier core).
// U symmetric -> transposed epilogue write lands U in straight layout.
__global__ void __launch_bounds__(256) k_mm1(
    const unsigned short* __restrict__ Ain_h, const unsigned short* __restrict__ Ain_l,
    const unsigned short* __restrict__ Bin_h, const unsigned short* __restrict__ Bin_l,
    unsigned short* __restrict__ Uh, unsigned short* __restrict__ Ul) {
  const int bid = blockIdx.x;
  const int z = bid & 7;
  const int t6 = bid >> 3;
  const int tr = (t6 >> 3) * 128, tc = (t6 & 7) * 128;
  const size_t MAT = (size_t)NN * NN;
  __shared__ unsigned short sm[32768];
  const int tid = threadIdx.x;
  const int wave = tid >> 6, lane = tid & 63;
  const int wm = (wave >> 1) * 64, wn = (wave & 1) * 64;
  const int q = lane >> 4, ln = lane & 15;
  const int rl = lane >> 3;
  const int gcol = ((lane & 7) ^ rl) << 3;
  const unsigned short* gp0;
  unsigned short* lb;
  if (wave == 0)      { gp0 = Ain_h + z * MAT + (size_t)tr * NN; lb = sm; }
  else if (wave == 1) { gp0 = Ain_l + z * MAT + (size_t)tr * NN; lb = sm + 8192; }
  else if (wave == 2) { gp0 = Bin_h + z * MAT + (size_t)tc * NN; lb = sm + 16384; }
  else                { gp0 = Bin_l + z * MAT + (size_t)tc * NN; lb = sm + 24576; }
  f32x4 acc[4][4];
  for (int i = 0; i < 4; ++i)
    for (int j = 0; j < 4; ++j) acc[i][j] = (f32x4){0.f, 0.f, 0.f, 0.f};
  const int swz = (ln & 7);
  for (int kc = 0; kc < NN; kc += 64) {
    __syncthreads();
    const unsigned short* gpk = gp0 + kc + gcol;
    for (int t = 0; t < 16; ++t)
      gload_lds16(gpk + (size_t)(t * 8 + rl) * NN, lb + t * 512);
    __syncthreads();
    for (int ks = 0; ks < 2; ++ks) {
      const int gq = ((ks * 4 + q) ^ swz) << 3;
      bf16x8 fah[4], fal[4], fbh[4], fbl[4];
      for (int i = 0; i < 4; ++i) {
        int off = (wm + i * 16 + ln) * 64 + gq;
        fah[i] = *(const bf16x8*)&sm[off];
        fal[i] = *(const bf16x8*)&sm[8192 + off];
      }
      for (int j = 0; j < 4; ++j) {
        int off = (wn + j * 16 + ln) * 64 + gq;
        fbh[j] = *(const bf16x8*)&sm[16384 + off];
        fbl[j] = *(const bf16x8*)&sm[24576 + off];
      }
      for (int i = 0; i < 4; ++i)
        for (int j = 0; j < 4; ++j) {
          acc[i][j] = __builtin_amdgcn_mfma_f32_16x16x32_bf16(fah[i], fbh[j], acc[i][j], 0, 0, 0);
          acc[i][j] = __builtin_amdgcn_mfma_f32_16x16x32_bf16(fah[i], fbl[j], acc[i][j], 0, 0, 0);
          acc[i][j] = __builtin_amdgcn_mfma_f32_16x16x32_bf16(fal[i], fbh[j], acc[i][j], 0, 0, 0);
        }
    }
  }
  unsigned short* cth = Uh + z * MAT;
  unsigned short* ctl = Ul + z * MAT;
  for (int i = 0; i < 4; ++i) {
    int m0 = tr + wm + i * 16 + q * 4;
    for (int j = 0; j < 4; ++j) {
      int n = tc + wn + j * 16 + ln;
      ushort4 h4, l4;
      unsigned short hs[4], ls[4];
      for (int reg = 0; reg < 4; ++reg) {
        float v = acc[i][j][reg];
        hs[reg] = f2bu(v);
        ls[reg] = f2bu(v - bu2f(hs[reg]));
      }
      h4.x = hs[0]; h4.y = hs[1]; h4.z = hs[2]; h4.w = hs[3];
      l4.x = ls[0]; l4.y = ls[1]; l4.z = ls[2]; l4.w = ls[3];
      *(ushort4*)&cth[(size_t)n * NN + m0] = h4;
      *(ushort4*)&ctl[(size_t)n * NN + m0] = l4;
    }
  }
}

// MFMA GEMM2: V = U * (M D^-1)^T (split bf16, proven core) with FUSED combine:
// S[i][j] = 0.5*(invd_i+invd_j)*(M + 0.8U + 0.64V)[i][j] written directly.
__global__ void __launch_bounds__(256) k_mm2(
    const unsigned short* __restrict__ Ain_h, const unsigned short* __restrict__ Ain_l,
    const unsigned short* __restrict__ Bin_h, const unsigned short* __restrict__ Bin_l,
    const unsigned short* __restrict__ Mhp, const unsigned short* __restrict__ Mlp,
    const float* __restrict__ invd, float* __restrict__ S) {
  const int bid = blockIdx.x;
  const int z = bid & 7;
  const int t6 = bid >> 3;
  const int tr = (t6 >> 3) * 128, tc = (t6 & 7) * 128;
  const size_t MAT = (size_t)NN * NN;
  __shared__ unsigned short sm[32768];
  const int tid = threadIdx.x;
  const int wave = tid >> 6, lane = tid & 63;
  const int wm = (wave >> 1) * 64, wn = (wave & 1) * 64;
  const int q = lane >> 4, ln = lane & 15;
  const int rl = lane >> 3;
  const int gcol = ((lane & 7) ^ rl) << 3;
  const unsigned short* gp0;
  unsigned short* lb;
  if (wave == 0)      { gp0 = Ain_h + z * MAT + (size_t)tr * NN; lb = sm; }
  else if (wave == 1) { gp0 = Ain_l + z * MAT + (size_t)tr * NN; lb = sm + 8192; }
  else if (wave == 2) { gp0 = Bin_h + z * MAT + (size_t)tc * NN; lb = sm + 16384; }
  else                { gp0 = Bin_l + z * MAT + (size_t)tc * NN; lb = sm + 24576; }
  f32x4 acc[4][4];
  for (int i = 0; i < 4; ++i)
    for (int j = 0; j < 4; ++j) acc[i][j] = (f32x4){0.f, 0.f, 0.f, 0.f};
  const int swz = (ln & 7);
  for (int kc = 0; kc < NN; kc += 64) {
    __syncthreads();
    const unsigned short* gpk = gp0 + kc + gcol;
    for (int t = 0; t < 16; ++t)
      gload_lds16(gpk + (size_t)(t * 8 + rl) * NN, lb + t * 512);
    __syncthreads();
    for (int ks = 0; ks < 2; ++ks) {
      const int gq = ((ks * 4 + q) ^ swz) << 3;
      bf16x8 fah[4], fal[4], fbh[4], fbl[4];
      for (int i = 0; i < 4; ++i) {
        int off = (wm + i * 16 + ln) * 64 + gq;
        fah[i] = *(const bf16x8*)&sm[off];
        fal[i] = *(const bf16x8*)&sm[8192 + off];
      }
      for (int j = 0; j < 4; ++j) {
        int off = (wn + j * 16 + ln) * 64 + gq;
        fbh[j] = *(const bf16x8*)&sm[16384 + off];
        fbl[j] = *(const bf16x8*)&sm[24576 + off];
      }
      for (int i = 0; i < 4; ++i)
        for (int j = 0; j < 4; ++j) {
          acc[i][j] = __builtin_amdgcn_mfma_f32_16x16x32_bf16(fah[i], fbh[j], acc[i][j], 0, 0, 0);
          acc[i][j] = __builtin_amdgcn_mfma_f32_16x16x32_bf16(fah[i], fbl[j], acc[i][j], 0, 0, 0);
          acc[i][j] = __builtin_amdgcn_mfma_f32_16x16x32_bf16(fal[i], fbh[j], acc[i][j], 0, 0, 0);
        }
    }
  }
  // fused combine epilogue: V in acc; read M, U tiles + invd; write final S.
  const unsigned short* mh = Mhp + z * MAT;
  const unsigned short* ml = Mlp + z * MAT;
  const unsigned short* uh = Ain_h + z * MAT;  // A-operand IS U
  const unsigned short* ul = Ain_l + z * MAT;
  const float* idz = invd + (z << 10);
  float* Sb = S + z * MAT;
  for (int i = 0; i < 4; ++i) {
    int m0 = tr + wm + i * 16 + q * 4;
    float idr[4];
    for (int reg = 0; reg < 4; ++reg) idr[reg] = idz[m0 + reg];
    for (int j = 0; j < 4; ++j) {
      int n = tc + wn + j * 16 + ln;
      float idc = idz[n];
      for (int reg = 0; reg < 4; ++reg) {
        size_t off = (size_t)(m0 + reg) * NN + n;
        float mval = bu2f(mh[off]) + bu2f(ml[off]);
        float uval = bu2f(uh[off]) + bu2f(ul[off]);
        Sb[off] = 0.5f * (idr[reg] + idc) *
                  (mval + 0.8f * uval + 0.64f * acc[i][j][reg]);
      }
    }
  }
}

// thr[b] = min(diag) - mean(diag[:-1] - offdiag)
__global__ void __launch_bounds__(256) k_thr(const float* __restrict__ S,
                                             float* __restrict__ thr) {
  const int b = blockIdx.x;
  const float* Sb = S + (size_t)b * NN * NN;
  const int tid = threadIdx.x;
  float mn = 3.0e38f;
  float rsum = 0.f;
  for (int n = tid; n < NN; n += 256) {
    float d = Sb[(size_t)n * NN + n];
    mn = fminf(mn, d);
    if (n < NN - 1) rsum += d - Sb[(size_t)n * NN + n + 1];
  }
  __shared__ float tmp[4];
  float mtot = blockMinF(mn, tmp);
  float stot = blockSumF(rsum, tmp);
  if (tid == 0) thr[b] = mtot - stot / 1023.0f;
}

__global__ void __launch_bounds__(256) k_stats(const float* __restrict__ S,
                                               const float* __restrict__ thr,
                                               const float* __restrict__ wh1,
                                               const float* __restrict__ wh2,
                                               float* __restrict__ meanv,
                                               float* __restrict__ rstdv) {
  const int n = blockIdx.x;
  const int tid = threadIdx.x;
  double s1 = 0.0, s2 = 0.0;
  for (int b = 0; b < BB; ++b) {
    float t = thr[b];
    float w1 = wh1[b * NN + n];
    const float* Srow = S + ((size_t)b * NN + n) * NN;
    const float* w2p = wh2 + b * NN;
    for (int m = tid; m < NN; m += 256) {
      float e = w1 + w2p[m];
      e = (e > 0.f) ? e : 0.01f * e;
      float att = (Srow[m] > t) ? e : NEGV;
      s1 += (double)att;
      s2 += (double)att * (double)att;
    }
  }
  __shared__ double red[256];
  red[tid] = s1;
  __syncthreads();
  for (int s = 128; s > 0; s >>= 1) {
    if (tid < s) red[tid] += red[tid + s];
    __syncthreads();
  }
  double t1 = red[0];
  __syncthreads();
  red[tid] = s2;
  __syncthreads();
  for (int s = 128; s > 0; s >>= 1) {
    if (tid < s) red[tid] += red[tid + s];
    __syncthreads();
  }
  double t2 = red[0];
  if (tid == 0) {
    double mean = t1 / 8192.0;
    double var = t2 / 8192.0 - mean * mean;
    if (var < 0.0) var = 0.0;
    meanv[n] = (float)mean;
    rstdv[n] = (float)(1.0 / sqrt(var + 1e-5));
  }
}

__global__ void __launch_bounds__(256) k_out(const float* __restrict__ S,
                                             const float* __restrict__ thr,
                                             const float* __restrict__ wh1,
                                             const float* __restrict__ wh2,
                                             const float* __restrict__ meanv,
                                             const float* __restrict__ rstdv,
                                             const float* __restrict__ flag,
                                             void* outv) {
  const int bn = blockIdx.x;
  const int b = bn >> 10;
  const int n = bn & 1023;
  const int tid = threadIdx.x;
  const bool f32m = (flag[0] != 0.0f);
  const float t = thr[b];
  const float w1 = wh1[bn];
  const float* Srow = S + (size_t)bn * NN;
  const float* w2p = wh2 + b * NN;
  float v[4];
  float mx = -3.0e38f;
  for (int w = 0; w < 4; ++w) {
    int m = tid + (w << 8);
    float e = w1 + w2p[m];
    e = (e > 0.f) ? e : 0.01f * e;
    float att = (Srow[m] > t) ? e : NEGV;
    float vv = (att - meanv[n]) * rstdv[n];
    v[w] = vv;
    mx = fmaxf(mx, vv);
  }
  __shared__ float tmp[4];
  float gmx = blockMaxF(mx, tmp);
  float sum = 0.f;
  for (int w = 0; w < 4; ++w) {
    v[w] = __expf(v[w] - gmx);
    sum += v[w];
  }
  float gsum = blockSumF(sum, tmp);
  for (int w = 0; w < 4; ++w) {
    int m = tid + (w << 8);
    float val = v[w] / gsum;
    if (f32m) {
      ((float*)outv)[(size_t)bn * NN + m] = val;
    } else {
      ((bf16*)outv)[(size_t)bn * NN + m] = __float2bfloat16(val);
    }
  }
}

extern "C" void kernel_launch(void* const* d_in, const int* in_sizes, int n_in,
                              void* d_out, int out_size, void* d_ws,
                              size_t ws_size, hipStream_t stream) {
  float* ws = (float*)d_ws;

  float* sq = ws;              // 8192
  float* wh1 = ws + 8192;      // 8192
  float* wh2 = ws + 16384;     // 8192
  float* thr = ws + 24576;     // 8
  float* meanv = ws + 24608;   // 1024
  float* rstdv = ws + 25632;   // 1024
  float* flag = ws + 26656;    // 8
  float* invd = ws + 26664;    // 8192
  float* rsum = ws + 40960;    // 8192
  float* h = ws + 65536;       // 524288

  unsigned short* Mh = (unsigned short*)(ws + 589824);
  unsigned short* Ml = (unsigned short*)(ws + 4784128);
  unsigned short* ATh = (unsigned short*)(ws + 8978432);
  unsigned short* ATl = (unsigned short*)(ws + 13172736);
  unsigned short* Uh = (unsigned short*)(ws + 17367040);
  unsigned short* Ul = (unsigned short*)(ws + 21561344);
  float* Sf = ws + 25755648;  // 8388608 floats (final S)
  const size_t needed_fast = (25755648ull + 8388608ull) * 4ull;

  if (ws_size < needed_fast) {
    k_fill<<<dim3(2048), 256, 0, stream>>>((unsigned short*)d_out, out_size,
                                           (unsigned short)0xBF80);
    return;
  }

  k_detect<<<dim3(1), 256, 0, stream>>>((const unsigned short*)d_in[0], flag);
  k_h<<<dim3(BB * NN), 64, 0, stream>>>(d_in[0], d_in[1], d_in[2], flag, h, sq,
                                        wh1, wh2);
  k_zero<<<dim3(32), 256, 0, stream>>>(rsum, BB * NN);
  k_g<<<dim3(16, 16, BB), 256, 0, stream>>>(h, sq, Mh, Ml, rsum);
  k_recip<<<dim3(32), 256, 0, stream>>>(rsum, invd);
  k_at<<<dim3(BB * NN), 256, 0, stream>>>(Mh, Ml, invd, ATh, ATl);
  k_mm1<<<dim3(512), 256, 0, stream>>>(Mh, Ml, ATh, ATl, Uh, Ul);
  k_mm2<<<dim3(512), 256, 0, stream>>>(Uh, Ul, ATh, ATl, Mh, Ml, invd, Sf);
  k_thr<<<dim3(BB), 256, 0, stream>>>(Sf, thr);
  k_stats<<<dim3(NN), 256, 0, stream>>>(Sf, thr, wh1, wh2, meanv, rstdv);
  k_out<<<dim3(BB * NN), 256, 0, stream>>>(Sf, thr, wh1, wh2, meanv, rstdv,
                                           flag, d_out);
}

// Round 3
// 253.595 us; speedup vs baseline: 1.2038x; 1.0342x over previous
//
#include <hip/hip_runtime.h>
#include <hip/hip_bf16.h>

#define BB 8
#define NN 1024
#define FIN 256
#define FOUT 64
#define NEGV (-9000000000000000.0f)

typedef __hip_bfloat16 bf16;
typedef short bf16x8 __attribute__((ext_vector_type(8)));
typedef float f32x4 __attribute__((ext_vector_type(4)));

__device__ __forceinline__ float b2f(bf16 v) { return __bfloat162float(v); }
__device__ __forceinline__ float bu2f(unsigned short u) {
  union { unsigned int i; float f; } c;
  c.i = ((unsigned int)u) << 16;
  return c.f;
}
__device__ __forceinline__ unsigned short f2bu(float v) {
  bf16 t = __float2bfloat16(v);
  return *(unsigned short*)&t;
}

// async global->LDS, 16B per lane; LDS dest is wave-uniform base (+lane*16 by HW)
__device__ __forceinline__ void gload_lds16(const unsigned short* g,
                                            unsigned short* l) {
  __builtin_amdgcn_global_load_lds(
      (__attribute__((address_space(1))) void*)(unsigned long long)(const void*)g,
      (__attribute__((address_space(3))) void*)l, 16, 0, 0);
}

__device__ __forceinline__ float waveRedSum(float v) {
  for (int d = 32; d; d >>= 1) v += __shfl_down(v, d);
  return v;
}
__device__ __forceinline__ float waveRedMax(float v) {
  for (int d = 32; d; d >>= 1) v = fmaxf(v, __shfl_down(v, d));
  return v;
}
__device__ __forceinline__ float waveRedMin(float v) {
  for (int d = 32; d; d >>= 1) v = fminf(v, __shfl_down(v, d));
  return v;
}

__device__ __forceinline__ float blockSumF(float v, float* tmp) {
  __syncthreads();
  v = waveRedSum(v);
  if ((threadIdx.x & 63) == 0) tmp[threadIdx.x >> 6] = v;
  __syncthreads();
  return tmp[0] + tmp[1] + tmp[2] + tmp[3];
}
__device__ __forceinline__ float blockMaxF(float v, float* tmp) {
  __syncthreads();
  v = waveRedMax(v);
  if ((threadIdx.x & 63) == 0) tmp[threadIdx.x >> 6] = v;
  __syncthreads();
  return fmaxf(fmaxf(tmp[0], tmp[1]), fmaxf(tmp[2], tmp[3]));
}
__device__ __forceinline__ float blockMinF(float v, float* tmp) {
  __syncthreads();
  v = waveRedMin(v);
  if ((threadIdx.x & 63) == 0) tmp[threadIdx.x >> 6] = v;
  __syncthreads();
  return fminf(fminf(tmp[0], tmp[1]), fminf(tmp[2], tmp[3]));
}

__global__ void k_fill(unsigned short* o, int n, unsigned short pat) {
  int i = blockIdx.x * blockDim.x + threadIdx.x;
  int stride = gridDim.x * blockDim.x;
  for (; i < n; i += stride) o[i] = pat;
}

__global__ void k_zero(float* p, int n) {
  int i = blockIdx.x * blockDim.x + threadIdx.x;
  if (i < n) p[i] = 0.f;
}

// dtype probe
__global__ void k_detect(const unsigned short* xu, float* flag) {
  const int tid = threadIdx.x;
  float mx = 0.0f, zc = 0.0f;
  for (int i = tid; i < 8192; i += 256) {
    unsigned short u = xu[i];
    float v = bu2f(u);
    if (u == 0 || u == 0x8000) zc += 1.0f;
    mx = fmaxf(mx, fabsf(v));
  }
  __shared__ float tmp[4];
  float gm = blockMaxF(mx, tmp);
  float gz = blockSumF(zc, tmp);
  if (tid == 0) flag[0] = (gm > 1.0e6f || gz > 2048.0f) ? 1.0f : 0.0f;
}

// h = x @ W per (b,n) row, emitted as split bf16 (hi/lo); sq = |h|^2 (exact f32);
// wh1 = h.a1; wh2 = h.a2
__global__ void __launch_bounds__(64) k_h(const void* xv, const void* Wv,
                                          const void* av,
                                          const float* __restrict__ flag,
                                          unsigned short* __restrict__ Hh,
                                          unsigned short* __restrict__ Hl,
                                          float* __restrict__ sq,
                                          float* __restrict__ wh1,
                                          float* __restrict__ wh2) {
  const int bn = blockIdx.x;
  const int o = threadIdx.x;
  const bool f32m = (flag[0] != 0.0f);
  __shared__ float xs[FIN];
  if (f32m) {
    const float* xr = (const float*)xv + (size_t)bn * FIN;
    for (int i = o; i < FIN; i += 64) xs[i] = xr[i];
  } else {
    const bf16* xr = (const bf16*)xv + (size_t)bn * FIN;
    for (int i = o; i < FIN; i += 64) xs[i] = b2f(xr[i]);
  }
  __syncthreads();
  float acc = 0.f;
  if (f32m) {
    const float* Wf = (const float*)Wv;
    for (int i = 0; i < FIN; ++i) acc += xs[i] * Wf[i * FOUT + o];
  } else {
    const bf16* Wb = (const bf16*)Wv;
    for (int i = 0; i < FIN; ++i) acc += xs[i] * b2f(Wb[i * FOUT + o]);
  }
  unsigned short hh = f2bu(acc);
  unsigned short hl = f2bu(acc - bu2f(hh));
  Hh[(size_t)bn * FOUT + o] = hh;
  Hl[(size_t)bn * FOUT + o] = hl;
  float a1, a2;
  if (f32m) {
    a1 = ((const float*)av)[o];
    a2 = ((const float*)av)[FOUT + o];
  } else {
    a1 = b2f(((const bf16*)av)[o]);
    a2 = b2f(((const bf16*)av)[FOUT + o]);
  }
  float s = waveRedSum(acc * acc);
  float w1 = waveRedSum(acc * a1);
  float w2 = waveRedSum(acc * a2);
  if (o == 0) {
    sq[bn] = s;
    wh1[bn] = w1;
    wh2[bn] = w2;
  }
}

// M[z] = exp(-dist) via MFMA G = h.h^T (split bf16, mm1-proven machinery, K=64).
// Exact 1.0 diag; writes hi/lo split (transposed layout == straight: M symmetric);
// accumulates exact-f32 row sums via q-group-reduced atomics.
__global__ void __launch_bounds__(256) k_g(const unsigned short* __restrict__ Hhp,
                                           const unsigned short* __restrict__ Hlp,
                                           const float* __restrict__ sq,
                                           unsigned short* __restrict__ Mh,
                                           unsigned short* __restrict__ Ml,
                                           float* __restrict__ rsum) {
  const int bid = blockIdx.x;
  const int z = bid & 7;
  const int t6 = bid >> 3;
  const int tr = (t6 >> 3) * 128, tc = (t6 & 7) * 128;
  const size_t MAT = (size_t)NN * NN;
  const float* sqb = sq + (z << 10);
  unsigned short* mhb = Mh + z * MAT;
  unsigned short* mlb = Ml + z * MAT;
  float* rsb = rsum + (z << 10);
  __shared__ unsigned short sm[32768];
  const int tid = threadIdx.x;
  const int wave = tid >> 6, lane = tid & 63;
  const int wm = (wave >> 1) * 64, wn = (wave & 1) * 64;
  const int q = lane >> 4, ln = lane & 15;
  const int rl = lane >> 3;
  const int gcol = ((lane & 7) ^ rl) << 3;
  const size_t HB = (size_t)z * NN * FOUT;
  const unsigned short* gp0;
  unsigned short* lb;
  if (wave == 0)      { gp0 = Hhp + HB + (size_t)tr * FOUT; lb = sm; }
  else if (wave == 1) { gp0 = Hlp + HB + (size_t)tr * FOUT; lb = sm + 8192; }
  else if (wave == 2) { gp0 = Hhp + HB + (size_t)tc * FOUT; lb = sm + 16384; }
  else                { gp0 = Hlp + HB + (size_t)tc * FOUT; lb = sm + 24576; }
  for (int t = 0; t < 16; ++t)
    gload_lds16(gp0 + (size_t)(t * 8 + rl) * FOUT + gcol, lb + t * 512);
  f32x4 acc[4][4];
  for (int i = 0; i < 4; ++i)
    for (int j = 0; j < 4; ++j) acc[i][j] = (f32x4){0.f, 0.f, 0.f, 0.f};
  __syncthreads();
  const int swz = (ln & 7);
  for (int ks = 0; ks < 2; ++ks) {
    const int gq = ((ks * 4 + q) ^ swz) << 3;
    bf16x8 fah[4], fal[4], fbh[4], fbl[4];
    for (int i = 0; i < 4; ++i) {
      int off = (wm + i * 16 + ln) * 64 + gq;
      fah[i] = *(const bf16x8*)&sm[off];
      fal[i] = *(const bf16x8*)&sm[8192 + off];
    }
    for (int j = 0; j < 4; ++j) {
      int off = (wn + j * 16 + ln) * 64 + gq;
      fbh[j] = *(const bf16x8*)&sm[16384 + off];
      fbl[j] = *(const bf16x8*)&sm[24576 + off];
    }
    for (int i = 0; i < 4; ++i)
      for (int j = 0; j < 4; ++j) {
        acc[i][j] = __builtin_amdgcn_mfma_f32_16x16x32_bf16(fah[i], fbh[j], acc[i][j], 0, 0, 0);
        acc[i][j] = __builtin_amdgcn_mfma_f32_16x16x32_bf16(fah[i], fbl[j], acc[i][j], 0, 0, 0);
        acc[i][j] = __builtin_amdgcn_mfma_f32_16x16x32_bf16(fal[i], fbh[j], acc[i][j], 0, 0, 0);
      }
  }
  // epilogue: d2 -> exp(-sqrt) -> split store (transposed == straight, M sym)
  float rs[4] = {0.f, 0.f, 0.f, 0.f};
  for (int i = 0; i < 4; ++i) {
    int m0 = tr + wm + i * 16 + q * 4;
    float sm0[4];
    for (int reg = 0; reg < 4; ++reg) sm0[reg] = sqb[m0 + reg];
    for (int j = 0; j < 4; ++j) {
      int n = tc + wn + j * 16 + ln;
      float sn = sqb[n];
      unsigned short hs[4], ls[4];
      for (int reg = 0; reg < 4; ++reg) {
        int m = m0 + reg;
        float d2 = sm0[reg] + sn - 2.0f * acc[i][j][reg];
        float v = (m == n) ? 1.0f : ((d2 > 0.0f) ? expf(-sqrtf(d2)) : 1.0f);
        rs[j] += v;
        hs[reg] = f2bu(v);
        ls[reg] = f2bu(v - bu2f(hs[reg]));
      }
      ushort4 h4, l4;
      h4.x = hs[0]; h4.y = hs[1]; h4.z = hs[2]; h4.w = hs[3];
      l4.x = ls[0]; l4.y = ls[1]; l4.z = ls[2]; l4.w = ls[3];
      *(ushort4*)&mhb[(size_t)n * NN + m0] = h4;
      *(ushort4*)&mlb[(size_t)n * NN + m0] = l4;
    }
  }
  // lanes {ln, ln+16, ln+32, ln+48} share n for fixed j: reduce across q first
  for (int j = 0; j < 4; ++j) {
    float v = rs[j];
    v += __shfl_xor(v, 16);
    v += __shfl_xor(v, 32);
    if (q == 0) {
      int n = tc + wn + j * 16 + ln;
      atomicAdd(&rsb[n], v);
    }
  }
}

// invd[i] = 1 / max(rsum[i], 1e-12)
__global__ void __launch_bounds__(256) k_recip(const float* __restrict__ rsum,
                                               float* __restrict__ invd) {
  int i = blockIdx.x * blockDim.x + threadIdx.x;
  if (i < BB * NN) invd[i] = 1.0f / fmaxf(rsum[i], 1e-12f);
}

// AT = M * D^-1 (column scale), split hi/lo. No transpose needed (M symmetric).
__global__ void __launch_bounds__(256) k_at(const unsigned short* __restrict__ Mh,
                                            const unsigned short* __restrict__ Ml,
                                            const float* __restrict__ invd,
                                            unsigned short* __restrict__ ATh,
                                            unsigned short* __restrict__ ATl) {
  const int bn = blockIdx.x;
  const int b = bn >> 10;
  const unsigned short* mh = Mh + (size_t)bn * NN;
  const unsigned short* ml = Ml + (size_t)bn * NN;
  const float* idv = invd + (b << 10);
  unsigned short* ah = ATh + (size_t)bn * NN;
  unsigned short* al = ATl + (size_t)bn * NN;
  const int c0 = threadIdx.x << 2;
  ushort4 h4 = *(const ushort4*)&mh[c0];
  ushort4 l4 = *(const ushort4*)&ml[c0];
  float4 iv = *(const float4*)&idv[c0];
  float v[4];
  v[0] = (bu2f(h4.x) + bu2f(l4.x)) * iv.x;
  v[1] = (bu2f(h4.y) + bu2f(l4.y)) * iv.y;
  v[2] = (bu2f(h4.z) + bu2f(l4.z)) * iv.z;
  v[3] = (bu2f(h4.w) + bu2f(l4.w)) * iv.w;
  unsigned short hs[4], ls[4];
  for (int k = 0; k < 4; ++k) {
    hs[k] = f2bu(v[k]);
    ls[k] = f2bu(v[k] - bu2f(hs[k]));
  }
  ushort4 oh, ol;
  oh.x = hs[0]; oh.y = hs[1]; oh.z = hs[2]; oh.w = hs[3];
  ol.x = ls[0]; ol.y = ls[1]; ol.z = ls[2]; ol.w = ls[3];
  *(ushort4*)&ah[c0] = oh;
  *(ushort4*)&al[c0] = ol;
}

// MFMA GEMM1: U = M * (M D^-1)^T = M D^-1 M (split bf16, proven 2-barrier core).
// U symmetric -> transposed epilogue write lands U in straight layout.
__global__ void __launch_bounds__(256) k_mm1(
    const unsigned short* __restrict__ Ain_h, const unsigned short* __restrict__ Ain_l,
    const unsigned short* __restrict__ Bin_h, const unsigned short* __restrict__ Bin_l,
    unsigned short* __restrict__ Uh, unsigned short* __restrict__ Ul) {
  const int bid = blockIdx.x;
  const int z = bid & 7;
  const int t6 = bid >> 3;
  const int tr = (t6 >> 3) * 128, tc = (t6 & 7) * 128;
  const size_t MAT = (size_t)NN * NN;
  __shared__ unsigned short sm[32768];
  const int tid = threadIdx.x;
  const int wave = tid >> 6, lane = tid & 63;
  const int wm = (wave >> 1) * 64, wn = (wave & 1) * 64;
  const int q = lane >> 4, ln = lane & 15;
  const int rl = lane >> 3;
  const int gcol = ((lane & 7) ^ rl) << 3;
  const unsigned short* gp0;
  unsigned short* lb;
  if (wave == 0)      { gp0 = Ain_h + z * MAT + (size_t)tr * NN; lb = sm; }
  else if (wave == 1) { gp0 = Ain_l + z * MAT + (size_t)tr * NN; lb = sm + 8192; }
  else if (wave == 2) { gp0 = Bin_h + z * MAT + (size_t)tc * NN; lb = sm + 16384; }
  else                { gp0 = Bin_l + z * MAT + (size_t)tc * NN; lb = sm + 24576; }
  f32x4 acc[4][4];
  for (int i = 0; i < 4; ++i)
    for (int j = 0; j < 4; ++j) acc[i][j] = (f32x4){0.f, 0.f, 0.f, 0.f};
  const int swz = (ln & 7);
  for (int kc = 0; kc < NN; kc += 64) {
    __syncthreads();
    const unsigned short* gpk = gp0 + kc + gcol;
    for (int t = 0; t < 16; ++t)
      gload_lds16(gpk + (size_t)(t * 8 + rl) * NN, lb + t * 512);
    __syncthreads();
    for (int ks = 0; ks < 2; ++ks) {
      const int gq = ((ks * 4 + q) ^ swz) << 3;
      bf16x8 fah[4], fal[4], fbh[4], fbl[4];
      for (int i = 0; i < 4; ++i) {
        int off = (wm + i * 16 + ln) * 64 + gq;
        fah[i] = *(const bf16x8*)&sm[off];
        fal[i] = *(const bf16x8*)&sm[8192 + off];
      }
      for (int j = 0; j < 4; ++j) {
        int off = (wn + j * 16 + ln) * 64 + gq;
        fbh[j] = *(const bf16x8*)&sm[16384 + off];
        fbl[j] = *(const bf16x8*)&sm[24576 + off];
      }
      for (int i = 0; i < 4; ++i)
        for (int j = 0; j < 4; ++j) {
          acc[i][j] = __builtin_amdgcn_mfma_f32_16x16x32_bf16(fah[i], fbh[j], acc[i][j], 0, 0, 0);
          acc[i][j] = __builtin_amdgcn_mfma_f32_16x16x32_bf16(fah[i], fbl[j], acc[i][j], 0, 0, 0);
          acc[i][j] = __builtin_amdgcn_mfma_f32_16x16x32_bf16(fal[i], fbh[j], acc[i][j], 0, 0, 0);
        }
    }
  }
  unsigned short* cth = Uh + z * MAT;
  unsigned short* ctl = Ul + z * MAT;
  for (int i = 0; i < 4; ++i) {
    int m0 = tr + wm + i * 16 + q * 4;
    for (int j = 0; j < 4; ++j) {
      int n = tc + wn + j * 16 + ln;
      ushort4 h4, l4;
      unsigned short hs[4], ls[4];
      for (int reg = 0; reg < 4; ++reg) {
        float v = acc[i][j][reg];
        hs[reg] = f2bu(v);
        ls[reg] = f2bu(v - bu2f(hs[reg]));
      }
      h4.x = hs[0]; h4.y = hs[1]; h4.z = hs[2]; h4.w = hs[3];
      l4.x = ls[0]; l4.y = ls[1]; l4.z = ls[2]; l4.w = ls[3];
      *(ushort4*)&cth[(size_t)n * NN + m0] = h4;
      *(ushort4*)&ctl[(size_t)n * NN + m0] = l4;
    }
  }
}

// MFMA GEMM2: V = U * (M D^-1)^T (split bf16, proven core) with FUSED combine:
// S[i][j] = 0.5*(invd_i+invd_j)*(M + 0.8U + 0.64V)[i][j] written directly.
__global__ void __launch_bounds__(256) k_mm2(
    const unsigned short* __restrict__ Ain_h, const unsigned short* __restrict__ Ain_l,
    const unsigned short* __restrict__ Bin_h, const unsigned short* __restrict__ Bin_l,
    const unsigned short* __restrict__ Mhp, const unsigned short* __restrict__ Mlp,
    const float* __restrict__ invd, float* __restrict__ S) {
  const int bid = blockIdx.x;
  const int z = bid & 7;
  const int t6 = bid >> 3;
  const int tr = (t6 >> 3) * 128, tc = (t6 & 7) * 128;
  const size_t MAT = (size_t)NN * NN;
  __shared__ unsigned short sm[32768];
  const int tid = threadIdx.x;
  const int wave = tid >> 6, lane = tid & 63;
  const int wm = (wave >> 1) * 64, wn = (wave & 1) * 64;
  const int q = lane >> 4, ln = lane & 15;
  const int rl = lane >> 3;
  const int gcol = ((lane & 7) ^ rl) << 3;
  const unsigned short* gp0;
  unsigned short* lb;
  if (wave == 0)      { gp0 = Ain_h + z * MAT + (size_t)tr * NN; lb = sm; }
  else if (wave == 1) { gp0 = Ain_l + z * MAT + (size_t)tr * NN; lb = sm + 8192; }
  else if (wave == 2) { gp0 = Bin_h + z * MAT + (size_t)tc * NN; lb = sm + 16384; }
  else                { gp0 = Bin_l + z * MAT + (size_t)tc * NN; lb = sm + 24576; }
  f32x4 acc[4][4];
  for (int i = 0; i < 4; ++i)
    for (int j = 0; j < 4; ++j) acc[i][j] = (f32x4){0.f, 0.f, 0.f, 0.f};
  const int swz = (ln & 7);
  for (int kc = 0; kc < NN; kc += 64) {
    __syncthreads();
    const unsigned short* gpk = gp0 + kc + gcol;
    for (int t = 0; t < 16; ++t)
      gload_lds16(gpk + (size_t)(t * 8 + rl) * NN, lb + t * 512);
    __syncthreads();
    for (int ks = 0; ks < 2; ++ks) {
      const int gq = ((ks * 4 + q) ^ swz) << 3;
      bf16x8 fah[4], fal[4], fbh[4], fbl[4];
      for (int i = 0; i < 4; ++i) {
        int off = (wm + i * 16 + ln) * 64 + gq;
        fah[i] = *(const bf16x8*)&sm[off];
        fal[i] = *(const bf16x8*)&sm[8192 + off];
      }
      for (int j = 0; j < 4; ++j) {
        int off = (wn + j * 16 + ln) * 64 + gq;
        fbh[j] = *(const bf16x8*)&sm[16384 + off];
        fbl[j] = *(const bf16x8*)&sm[24576 + off];
      }
      for (int i = 0; i < 4; ++i)
        for (int j = 0; j < 4; ++j) {
          acc[i][j] = __builtin_amdgcn_mfma_f32_16x16x32_bf16(fah[i], fbh[j], acc[i][j], 0, 0, 0);
          acc[i][j] = __builtin_amdgcn_mfma_f32_16x16x32_bf16(fah[i], fbl[j], acc[i][j], 0, 0, 0);
          acc[i][j] = __builtin_amdgcn_mfma_f32_16x16x32_bf16(fal[i], fbh[j], acc[i][j], 0, 0, 0);
        }
    }
  }
  // fused combine epilogue: V in acc; read M, U tiles + invd; write final S.
  const unsigned short* mh = Mhp + z * MAT;
  const unsigned short* ml = Mlp + z * MAT;
  const unsigned short* uh = Ain_h + z * MAT;  // A-operand IS U
  const unsigned short* ul = Ain_l + z * MAT;
  const float* idz = invd + (z << 10);
  float* Sb = S + z * MAT;
  for (int i = 0; i < 4; ++i) {
    int m0 = tr + wm + i * 16 + q * 4;
    float idr[4];
    for (int reg = 0; reg < 4; ++reg) idr[reg] = idz[m0 + reg];
    for (int j = 0; j < 4; ++j) {
      int n = tc + wn + j * 16 + ln;
      float idc = idz[n];
      for (int reg = 0; reg < 4; ++reg) {
        size_t off = (size_t)(m0 + reg) * NN + n;
        float mval = bu2f(mh[off]) + bu2f(ml[off]);
        float uval = bu2f(uh[off]) + bu2f(ul[off]);
        Sb[off] = 0.5f * (idr[reg] + idc) *
                  (mval + 0.8f * uval + 0.64f * acc[i][j][reg]);
      }
    }
  }
}

// thr[b] = min(diag) - mean(diag[:-1] - offdiag)
__global__ void __launch_bounds__(256) k_thr(const float* __restrict__ S,
                                             float* __restrict__ thr) {
  const int b = blockIdx.x;
  const float* Sb = S + (size_t)b * NN * NN;
  const int tid = threadIdx.x;
  float mn = 3.0e38f;
  float rsum = 0.f;
  for (int n = tid; n < NN; n += 256) {
    float d = Sb[(size_t)n * NN + n];
    mn = fminf(mn, d);
    if (n < NN - 1) rsum += d - Sb[(size_t)n * NN + n + 1];
  }
  __shared__ float tmp[4];
  float mtot = blockMinF(mn, tmp);
  float stot = blockSumF(rsum, tmp);
  if (tid == 0) thr[b] = mtot - stot / 1023.0f;
}

__global__ void __launch_bounds__(256) k_stats(const float* __restrict__ S,
                                               const float* __restrict__ thr,
                                               const float* __restrict__ wh1,
                                               const float* __restrict__ wh2,
                                               float* __restrict__ meanv,
                                               float* __restrict__ rstdv) {
  const int n = blockIdx.x;
  const int tid = threadIdx.x;
  double s1 = 0.0, s2 = 0.0;
  for (int b = 0; b < BB; ++b) {
    float t = thr[b];
    float w1 = wh1[b * NN + n];
    const float* Srow = S + ((size_t)b * NN + n) * NN;
    const float* w2p = wh2 + b * NN;
    for (int m = tid; m < NN; m += 256) {
      float e = w1 + w2p[m];
      e = (e > 0.f) ? e : 0.01f * e;
      float att = (Srow[m] > t) ? e : NEGV;
      s1 += (double)att;
      s2 += (double)att * (double)att;
    }
  }
  __shared__ double red[256];
  red[tid] = s1;
  __syncthreads();
  for (int s = 128; s > 0; s >>= 1) {
    if (tid < s) red[tid] += red[tid + s];
    __syncthreads();
  }
  double t1 = red[0];
  __syncthreads();
  red[tid] = s2;
  __syncthreads();
  for (int s = 128; s > 0; s >>= 1) {
    if (tid < s) red[tid] += red[tid + s];
    __syncthreads();
  }
  double t2 = red[0];
  if (tid == 0) {
    double mean = t1 / 8192.0;
    double var = t2 / 8192.0 - mean * mean;
    if (var < 0.0) var = 0.0;
    meanv[n] = (float)mean;
    rstdv[n] = (float)(1.0 / sqrt(var + 1e-5));
  }
}

__global__ void __launch_bounds__(256) k_out(const float* __restrict__ S,
                                             const float* __restrict__ thr,
                                             const float* __restrict__ wh1,
                                             const float* __restrict__ wh2,
                                             const float* __restrict__ meanv,
                                             const float* __restrict__ rstdv,
                                             const float* __restrict__ flag,
                                             void* outv) {
  const int bn = blockIdx.x;
  const int b = bn >> 10;
  const int n = bn & 1023;
  const int tid = threadIdx.x;
  const bool f32m = (flag[0] != 0.0f);
  const float t = thr[b];
  const float w1 = wh1[bn];
  const float* Srow = S + (size_t)bn * NN;
  const float* w2p = wh2 + b * NN;
  float v[4];
  float mx = -3.0e38f;
  for (int w = 0; w < 4; ++w) {
    int m = tid + (w << 8);
    float e = w1 + w2p[m];
    e = (e > 0.f) ? e : 0.01f * e;
    float att = (Srow[m] > t) ? e : NEGV;
    float vv = (att - meanv[n]) * rstdv[n];
    v[w] = vv;
    mx = fmaxf(mx, vv);
  }
  __shared__ float tmp[4];
  float gmx = blockMaxF(mx, tmp);
  float sum = 0.f;
  for (int w = 0; w < 4; ++w) {
    v[w] = __expf(v[w] - gmx);
    sum += v[w];
  }
  float gsum = blockSumF(sum, tmp);
  for (int w = 0; w < 4; ++w) {
    int m = tid + (w << 8);
    float val = v[w] / gsum;
    if (f32m) {
      ((float*)outv)[(size_t)bn * NN + m] = val;
    } else {
      ((bf16*)outv)[(size_t)bn * NN + m] = __float2bfloat16(val);
    }
  }
}

extern "C" void kernel_launch(void* const* d_in, const int* in_sizes, int n_in,
                              void* d_out, int out_size, void* d_ws,
                              size_t ws_size, hipStream_t stream) {
  float* ws = (float*)d_ws;

  float* sq = ws;              // 8192
  float* wh1 = ws + 8192;      // 8192
  float* wh2 = ws + 16384;     // 8192
  float* thr = ws + 24576;     // 8
  float* meanv = ws + 24608;   // 1024
  float* rstdv = ws + 25632;   // 1024
  float* flag = ws + 26656;    // 8
  float* invd = ws + 26664;    // 8192
  float* rsum = ws + 40960;    // 8192

  unsigned short* Hh = (unsigned short*)(ws + 65536);   // 524288 ushorts
  unsigned short* Hl = (unsigned short*)(ws + 327680);  // 524288 ushorts

  unsigned short* Mh = (unsigned short*)(ws + 589824);
  unsigned short* Ml = (unsigned short*)(ws + 4784128);
  unsigned short* ATh = (unsigned short*)(ws + 8978432);
  unsigned short* ATl = (unsigned short*)(ws + 13172736);
  unsigned short* Uh = (unsigned short*)(ws + 17367040);
  unsigned short* Ul = (unsigned short*)(ws + 21561344);
  float* Sf = ws + 25755648;  // 8388608 floats (final S)
  const size_t needed_fast = (25755648ull + 8388608ull) * 4ull;

  if (ws_size < needed_fast) {
    k_fill<<<dim3(2048), 256, 0, stream>>>((unsigned short*)d_out, out_size,
                                           (unsigned short)0xBF80);
    return;
  }

  k_detect<<<dim3(1), 256, 0, stream>>>((const unsigned short*)d_in[0], flag);
  k_h<<<dim3(BB * NN), 64, 0, stream>>>(d_in[0], d_in[1], d_in[2], flag, Hh, Hl,
                                        sq, wh1, wh2);
  k_zero<<<dim3(32), 256, 0, stream>>>(rsum, BB * NN);
  k_g<<<dim3(512), 256, 0, stream>>>(Hh, Hl, sq, Mh, Ml, rsum);
  k_recip<<<dim3(32), 256, 0, stream>>>(rsum, invd);
  k_at<<<dim3(BB * NN), 256, 0, stream>>>(Mh, Ml, invd, ATh, ATl);
  k_mm1<<<dim3(512), 256, 0, stream>>>(Mh, Ml, ATh, ATl, Uh, Ul);
  k_mm2<<<dim3(512), 256, 0, stream>>>(Uh, Ul, ATh, ATl, Mh, Ml, invd, Sf);
  k_thr<<<dim3(BB), 256, 0, stream>>>(Sf, thr);
  k_stats<<<dim3(NN), 256, 0, stream>>>(Sf, thr, wh1, wh2, meanv, rstdv);
  k_out<<<dim3(BB * NN), 256, 0, stream>>>(Sf, thr, wh1, wh2, meanv, rstdv,
                                           flag, d_out);
}

// Round 4
// 246.276 us; speedup vs baseline: 1.2395x; 1.0297x over previous
//
#include <hip/hip_runtime.h>
#include <hip/hip_bf16.h>

#define BB 8
#define NN 1024
#define FIN 256
#define FOUT 64
#define NEGV (-9000000000000000.0f)

typedef __hip_bfloat16 bf16;
typedef short bf16x8 __attribute__((ext_vector_type(8)));
typedef float f32x4 __attribute__((ext_vector_type(4)));

__device__ __forceinline__ float b2f(bf16 v) { return __bfloat162float(v); }
__device__ __forceinline__ float bu2f(unsigned short u) {
  union { unsigned int i; float f; } c;
  c.i = ((unsigned int)u) << 16;
  return c.f;
}
__device__ __forceinline__ unsigned short f2bu(float v) {
  bf16 t = __float2bfloat16(v);
  return *(unsigned short*)&t;
}

// async global->LDS, 16B per lane; LDS dest is wave-uniform base (+lane*16 by HW)
__device__ __forceinline__ void gload_lds16(const unsigned short* g,
                                            unsigned short* l) {
  __builtin_amdgcn_global_load_lds(
      (__attribute__((address_space(1))) void*)(unsigned long long)(const void*)g,
      (__attribute__((address_space(3))) void*)l, 16, 0, 0);
}

__device__ __forceinline__ float waveRedSum(float v) {
  for (int d = 32; d; d >>= 1) v += __shfl_down(v, d);
  return v;
}
__device__ __forceinline__ float waveRedMax(float v) {
  for (int d = 32; d; d >>= 1) v = fmaxf(v, __shfl_down(v, d));
  return v;
}
__device__ __forceinline__ float waveRedMin(float v) {
  for (int d = 32; d; d >>= 1) v = fminf(v, __shfl_down(v, d));
  return v;
}

__device__ __forceinline__ float blockSumF(float v, float* tmp) {
  __syncthreads();
  v = waveRedSum(v);
  if ((threadIdx.x & 63) == 0) tmp[threadIdx.x >> 6] = v;
  __syncthreads();
  return tmp[0] + tmp[1] + tmp[2] + tmp[3];
}
__device__ __forceinline__ float blockMaxF(float v, float* tmp) {
  __syncthreads();
  v = waveRedMax(v);
  if ((threadIdx.x & 63) == 0) tmp[threadIdx.x >> 6] = v;
  __syncthreads();
  return fmaxf(fmaxf(tmp[0], tmp[1]), fmaxf(tmp[2], tmp[3]));
}
__device__ __forceinline__ float blockMinF(float v, float* tmp) {
  __syncthreads();
  v = waveRedMin(v);
  if ((threadIdx.x & 63) == 0) tmp[threadIdx.x >> 6] = v;
  __syncthreads();
  return fminf(fminf(tmp[0], tmp[1]), fminf(tmp[2], tmp[3]));
}

__global__ void k_fill(unsigned short* o, int n, unsigned short pat) {
  int i = blockIdx.x * blockDim.x + threadIdx.x;
  int stride = gridDim.x * blockDim.x;
  for (; i < n; i += stride) o[i] = pat;
}

__global__ void k_zero(float* p, int n) {
  int i = blockIdx.x * blockDim.x + threadIdx.x;
  if (i < n) p[i] = 0.f;
}

// dtype probe
__global__ void k_detect(const unsigned short* xu, float* flag) {
  const int tid = threadIdx.x;
  float mx = 0.0f, zc = 0.0f;
  for (int i = tid; i < 8192; i += 256) {
    unsigned short u = xu[i];
    float v = bu2f(u);
    if (u == 0 || u == 0x8000) zc += 1.0f;
    mx = fmaxf(mx, fabsf(v));
  }
  __shared__ float tmp[4];
  float gm = blockMaxF(mx, tmp);
  float gz = blockSumF(zc, tmp);
  if (tid == 0) flag[0] = (gm > 1.0e6f || gz > 2048.0f) ? 1.0f : 0.0f;
}

// h = x @ W per (b,n) row, emitted as split bf16 (hi/lo); sq = |h|^2 (exact f32);
// wh1 = h.a1; wh2 = h.a2
__global__ void __launch_bounds__(64) k_h(const void* xv, const void* Wv,
                                          const void* av,
                                          const float* __restrict__ flag,
                                          unsigned short* __restrict__ Hh,
                                          unsigned short* __restrict__ Hl,
                                          float* __restrict__ sq,
                                          float* __restrict__ wh1,
                                          float* __restrict__ wh2) {
  const int bn = blockIdx.x;
  const int o = threadIdx.x;
  const bool f32m = (flag[0] != 0.0f);
  __shared__ float xs[FIN];
  if (f32m) {
    const float* xr = (const float*)xv + (size_t)bn * FIN;
    for (int i = o; i < FIN; i += 64) xs[i] = xr[i];
  } else {
    const bf16* xr = (const bf16*)xv + (size_t)bn * FIN;
    for (int i = o; i < FIN; i += 64) xs[i] = b2f(xr[i]);
  }
  __syncthreads();
  float acc = 0.f;
  if (f32m) {
    const float* Wf = (const float*)Wv;
    for (int i = 0; i < FIN; ++i) acc += xs[i] * Wf[i * FOUT + o];
  } else {
    const bf16* Wb = (const bf16*)Wv;
    for (int i = 0; i < FIN; ++i) acc += xs[i] * b2f(Wb[i * FOUT + o]);
  }
  unsigned short hh = f2bu(acc);
  unsigned short hl = f2bu(acc - bu2f(hh));
  Hh[(size_t)bn * FOUT + o] = hh;
  Hl[(size_t)bn * FOUT + o] = hl;
  float a1, a2;
  if (f32m) {
    a1 = ((const float*)av)[o];
    a2 = ((const float*)av)[FOUT + o];
  } else {
    a1 = b2f(((const bf16*)av)[o]);
    a2 = b2f(((const bf16*)av)[FOUT + o]);
  }
  float s = waveRedSum(acc * acc);
  float w1 = waveRedSum(acc * a1);
  float w2 = waveRedSum(acc * a2);
  if (o == 0) {
    sq[bn] = s;
    wh1[bn] = w1;
    wh2[bn] = w2;
  }
}

// Pass 1: rowsums of M = exp(-dist) via MFMA (no stores). M symmetric:
// column sums over the block's rows == row-sum partials. Proven k_g structure.
__global__ void __launch_bounds__(256) k_g0(const unsigned short* __restrict__ Hhp,
                                            const unsigned short* __restrict__ Hlp,
                                            const float* __restrict__ sq,
                                            float* __restrict__ rsum) {
  const int bid = blockIdx.x;
  const int z = bid & 7;
  const int t6 = bid >> 3;
  const int tr = (t6 >> 3) * 128, tc = (t6 & 7) * 128;
  const float* sqb = sq + (z << 10);
  float* rsb = rsum + (z << 10);
  __shared__ unsigned short sm[32768];
  const int tid = threadIdx.x;
  const int wave = tid >> 6, lane = tid & 63;
  const int wm = (wave >> 1) * 64, wn = (wave & 1) * 64;
  const int q = lane >> 4, ln = lane & 15;
  const int rl = lane >> 3;
  const int gcol = ((lane & 7) ^ rl) << 3;
  const size_t HB = (size_t)z * NN * FOUT;
  const unsigned short* gp0;
  unsigned short* lb;
  if (wave == 0)      { gp0 = Hhp + HB + (size_t)tr * FOUT; lb = sm; }
  else if (wave == 1) { gp0 = Hlp + HB + (size_t)tr * FOUT; lb = sm + 8192; }
  else if (wave == 2) { gp0 = Hhp + HB + (size_t)tc * FOUT; lb = sm + 16384; }
  else                { gp0 = Hlp + HB + (size_t)tc * FOUT; lb = sm + 24576; }
  for (int t = 0; t < 16; ++t)
    gload_lds16(gp0 + (size_t)(t * 8 + rl) * FOUT + gcol, lb + t * 512);
  f32x4 acc[4][4];
  for (int i = 0; i < 4; ++i)
    for (int j = 0; j < 4; ++j) acc[i][j] = (f32x4){0.f, 0.f, 0.f, 0.f};
  __syncthreads();
  const int swz = (ln & 7);
  for (int ks = 0; ks < 2; ++ks) {
    const int gq = ((ks * 4 + q) ^ swz) << 3;
    bf16x8 fah[4], fal[4], fbh[4], fbl[4];
    for (int i = 0; i < 4; ++i) {
      int off = (wm + i * 16 + ln) * 64 + gq;
      fah[i] = *(const bf16x8*)&sm[off];
      fal[i] = *(const bf16x8*)&sm[8192 + off];
    }
    for (int j = 0; j < 4; ++j) {
      int off = (wn + j * 16 + ln) * 64 + gq;
      fbh[j] = *(const bf16x8*)&sm[16384 + off];
      fbl[j] = *(const bf16x8*)&sm[24576 + off];
    }
    for (int i = 0; i < 4; ++i)
      for (int j = 0; j < 4; ++j) {
        acc[i][j] = __builtin_amdgcn_mfma_f32_16x16x32_bf16(fah[i], fbh[j], acc[i][j], 0, 0, 0);
        acc[i][j] = __builtin_amdgcn_mfma_f32_16x16x32_bf16(fah[i], fbl[j], acc[i][j], 0, 0, 0);
        acc[i][j] = __builtin_amdgcn_mfma_f32_16x16x32_bf16(fal[i], fbh[j], acc[i][j], 0, 0, 0);
      }
  }
  float rs[4] = {0.f, 0.f, 0.f, 0.f};
  for (int i = 0; i < 4; ++i) {
    int m0 = tr + wm + i * 16 + q * 4;
    float sm0[4];
    for (int reg = 0; reg < 4; ++reg) sm0[reg] = sqb[m0 + reg];
    for (int j = 0; j < 4; ++j) {
      int n = tc + wn + j * 16 + ln;
      float sn = sqb[n];
      for (int reg = 0; reg < 4; ++reg) {
        int m = m0 + reg;
        float d2 = sm0[reg] + sn - 2.0f * acc[i][j][reg];
        float v = (m == n) ? 1.0f : ((d2 > 0.0f) ? expf(-sqrtf(d2)) : 1.0f);
        rs[j] += v;
      }
    }
  }
  for (int j = 0; j < 4; ++j) {
    float v = rs[j];
    v += __shfl_xor(v, 16);
    v += __shfl_xor(v, 32);
    if (q == 0) {
      int n = tc + wn + j * 16 + ln;
      atomicAdd(&rsb[n], v);
    }
  }
}

// dcl[i] = max(rsum,1e-12); isq[i] = 1/sqrt(dcl)
__global__ void __launch_bounds__(256) k_scal(const float* __restrict__ rsum,
                                              float* __restrict__ dcl,
                                              float* __restrict__ isq) {
  int i = blockIdx.x * blockDim.x + threadIdx.x;
  if (i < BB * NN) {
    float r = fmaxf(rsum[i], 1e-12f);
    dcl[i] = r;
    isq[i] = 1.0f / sqrtf(r);
  }
}

// Pass 2: W = D^-1/2 M D^-1/2 via MFMA recompute, split bf16 store
// (transposed store == straight: W symmetric). Proven k_g structure.
__global__ void __launch_bounds__(256) k_gw(const unsigned short* __restrict__ Hhp,
                                            const unsigned short* __restrict__ Hlp,
                                            const float* __restrict__ sq,
                                            const float* __restrict__ isq,
                                            unsigned short* __restrict__ Wh,
                                            unsigned short* __restrict__ Wl) {
  const int bid = blockIdx.x;
  const int z = bid & 7;
  const int t6 = bid >> 3;
  const int tr = (t6 >> 3) * 128, tc = (t6 & 7) * 128;
  const size_t MAT = (size_t)NN * NN;
  const float* sqb = sq + (z << 10);
  const float* isqb = isq + (z << 10);
  unsigned short* whb = Wh + z * MAT;
  unsigned short* wlb = Wl + z * MAT;
  __shared__ unsigned short sm[32768];
  const int tid = threadIdx.x;
  const int wave = tid >> 6, lane = tid & 63;
  const int wm = (wave >> 1) * 64, wn = (wave & 1) * 64;
  const int q = lane >> 4, ln = lane & 15;
  const int rl = lane >> 3;
  const int gcol = ((lane & 7) ^ rl) << 3;
  const size_t HB = (size_t)z * NN * FOUT;
  const unsigned short* gp0;
  unsigned short* lb;
  if (wave == 0)      { gp0 = Hhp + HB + (size_t)tr * FOUT; lb = sm; }
  else if (wave == 1) { gp0 = Hlp + HB + (size_t)tr * FOUT; lb = sm + 8192; }
  else if (wave == 2) { gp0 = Hhp + HB + (size_t)tc * FOUT; lb = sm + 16384; }
  else                { gp0 = Hlp + HB + (size_t)tc * FOUT; lb = sm + 24576; }
  for (int t = 0; t < 16; ++t)
    gload_lds16(gp0 + (size_t)(t * 8 + rl) * FOUT + gcol, lb + t * 512);
  f32x4 acc[4][4];
  for (int i = 0; i < 4; ++i)
    for (int j = 0; j < 4; ++j) acc[i][j] = (f32x4){0.f, 0.f, 0.f, 0.f};
  __syncthreads();
  const int swz = (ln & 7);
  for (int ks = 0; ks < 2; ++ks) {
    const int gq = ((ks * 4 + q) ^ swz) << 3;
    bf16x8 fah[4], fal[4], fbh[4], fbl[4];
    for (int i = 0; i < 4; ++i) {
      int off = (wm + i * 16 + ln) * 64 + gq;
      fah[i] = *(const bf16x8*)&sm[off];
      fal[i] = *(const bf16x8*)&sm[8192 + off];
    }
    for (int j = 0; j < 4; ++j) {
      int off = (wn + j * 16 + ln) * 64 + gq;
      fbh[j] = *(const bf16x8*)&sm[16384 + off];
      fbl[j] = *(const bf16x8*)&sm[24576 + off];
    }
    for (int i = 0; i < 4; ++i)
      for (int j = 0; j < 4; ++j) {
        acc[i][j] = __builtin_amdgcn_mfma_f32_16x16x32_bf16(fah[i], fbh[j], acc[i][j], 0, 0, 0);
        acc[i][j] = __builtin_amdgcn_mfma_f32_16x16x32_bf16(fah[i], fbl[j], acc[i][j], 0, 0, 0);
        acc[i][j] = __builtin_amdgcn_mfma_f32_16x16x32_bf16(fal[i], fbh[j], acc[i][j], 0, 0, 0);
      }
  }
  for (int i = 0; i < 4; ++i) {
    int m0 = tr + wm + i * 16 + q * 4;
    float sm0[4], im[4];
    for (int reg = 0; reg < 4; ++reg) {
      sm0[reg] = sqb[m0 + reg];
      im[reg] = isqb[m0 + reg];
    }
    for (int j = 0; j < 4; ++j) {
      int n = tc + wn + j * 16 + ln;
      float sn = sqb[n];
      float isn = isqb[n];
      unsigned short hs[4], ls[4];
      for (int reg = 0; reg < 4; ++reg) {
        int m = m0 + reg;
        float d2 = sm0[reg] + sn - 2.0f * acc[i][j][reg];
        float v = (m == n) ? 1.0f : ((d2 > 0.0f) ? expf(-sqrtf(d2)) : 1.0f);
        float vw = v * im[reg] * isn;
        hs[reg] = f2bu(vw);
        ls[reg] = f2bu(vw - bu2f(hs[reg]));
      }
      ushort4 h4, l4;
      h4.x = hs[0]; h4.y = hs[1]; h4.z = hs[2]; h4.w = hs[3];
      l4.x = ls[0]; l4.y = ls[1]; l4.z = ls[2]; l4.w = ls[3];
      *(ushort4*)&whb[(size_t)n * NN + m0] = h4;
      *(ushort4*)&wlb[(size_t)n * NN + m0] = l4;
    }
  }
}

// MFMA GEMM1: U = W * W^T = W^2 (symmetric). Upper-triangle tile pairs only
// (36 per z); straight write covers block (tj,ti), mirror covers (ti,tj).
__global__ void __launch_bounds__(256) k_mm1(
    const unsigned short* __restrict__ Wh, const unsigned short* __restrict__ Wl,
    unsigned short* __restrict__ Uh, unsigned short* __restrict__ Ul) {
  const int bid = blockIdx.x;
  const int z = bid & 7;
  int p = bid >> 3;
  int ti = 0, rem = p;
  while (rem >= 8 - ti) { rem -= 8 - ti; ++ti; }
  const int tj = ti + rem;
  const int tr = ti * 128, tc = tj * 128;
  const size_t MAT = (size_t)NN * NN;
  __shared__ unsigned short sm[32768];
  const int tid = threadIdx.x;
  const int wave = tid >> 6, lane = tid & 63;
  const int wm = (wave >> 1) * 64, wn = (wave & 1) * 64;
  const int q = lane >> 4, ln = lane & 15;
  const int rl = lane >> 3;
  const int gcol = ((lane & 7) ^ rl) << 3;
  const unsigned short* gp0;
  unsigned short* lb;
  if (wave == 0)      { gp0 = Wh + z * MAT + (size_t)tr * NN; lb = sm; }
  else if (wave == 1) { gp0 = Wl + z * MAT + (size_t)tr * NN; lb = sm + 8192; }
  else if (wave == 2) { gp0 = Wh + z * MAT + (size_t)tc * NN; lb = sm + 16384; }
  else                { gp0 = Wl + z * MAT + (size_t)tc * NN; lb = sm + 24576; }
  f32x4 acc[4][4];
  for (int i = 0; i < 4; ++i)
    for (int j = 0; j < 4; ++j) acc[i][j] = (f32x4){0.f, 0.f, 0.f, 0.f};
  const int swz = (ln & 7);
  for (int kc = 0; kc < NN; kc += 64) {
    __syncthreads();
    const unsigned short* gpk = gp0 + kc + gcol;
    for (int t = 0; t < 16; ++t)
      gload_lds16(gpk + (size_t)(t * 8 + rl) * NN, lb + t * 512);
    __syncthreads();
    for (int ks = 0; ks < 2; ++ks) {
      const int gq = ((ks * 4 + q) ^ swz) << 3;
      bf16x8 fah[4], fal[4], fbh[4], fbl[4];
      for (int i = 0; i < 4; ++i) {
        int off = (wm + i * 16 + ln) * 64 + gq;
        fah[i] = *(const bf16x8*)&sm[off];
        fal[i] = *(const bf16x8*)&sm[8192 + off];
      }
      for (int j = 0; j < 4; ++j) {
        int off = (wn + j * 16 + ln) * 64 + gq;
        fbh[j] = *(const bf16x8*)&sm[16384 + off];
        fbl[j] = *(const bf16x8*)&sm[24576 + off];
      }
      for (int i = 0; i < 4; ++i)
        for (int j = 0; j < 4; ++j) {
          acc[i][j] = __builtin_amdgcn_mfma_f32_16x16x32_bf16(fah[i], fbh[j], acc[i][j], 0, 0, 0);
          acc[i][j] = __builtin_amdgcn_mfma_f32_16x16x32_bf16(fah[i], fbl[j], acc[i][j], 0, 0, 0);
          acc[i][j] = __builtin_amdgcn_mfma_f32_16x16x32_bf16(fal[i], fbh[j], acc[i][j], 0, 0, 0);
        }
    }
  }
  unsigned short* cth = Uh + z * MAT;
  unsigned short* ctl = Ul + z * MAT;
  const bool mirror = (ti != tj);
  for (int i = 0; i < 4; ++i) {
    int m0 = tr + wm + i * 16 + q * 4;
    for (int j = 0; j < 4; ++j) {
      int n = tc + wn + j * 16 + ln;
      ushort4 h4, l4;
      unsigned short hs[4], ls[4];
      for (int reg = 0; reg < 4; ++reg) {
        float v = acc[i][j][reg];
        hs[reg] = f2bu(v);
        ls[reg] = f2bu(v - bu2f(hs[reg]));
      }
      h4.x = hs[0]; h4.y = hs[1]; h4.z = hs[2]; h4.w = hs[3];
      l4.x = ls[0]; l4.y = ls[1]; l4.z = ls[2]; l4.w = ls[3];
      *(ushort4*)&cth[(size_t)n * NN + m0] = h4;
      *(ushort4*)&ctl[(size_t)n * NN + m0] = l4;
      if (mirror) {
        for (int reg = 0; reg < 4; ++reg) {
          cth[(size_t)(m0 + reg) * NN + n] = hs[reg];
          ctl[(size_t)(m0 + reg) * NN + n] = ls[reg];
        }
      }
    }
  }
}

// MFMA GEMM2: X3 = U * W^T = W^3 (symmetric), with FUSED combine:
// S[i][j] = 0.5*(d_i+d_j)*isq_i*isq_j*(W + 0.8U + 0.64*W^3)[i][j].
// Upper-triangle pairs; straight covers (ti,tj), mirror float4 covers (tj,ti).
__global__ void __launch_bounds__(256) k_mm2(
    const unsigned short* __restrict__ Uh, const unsigned short* __restrict__ Ul,
    const unsigned short* __restrict__ Wh, const unsigned short* __restrict__ Wl,
    const float* __restrict__ dcl, const float* __restrict__ isq,
    float* __restrict__ S) {
  const int bid = blockIdx.x;
  const int z = bid & 7;
  int p = bid >> 3;
  int ti = 0, rem = p;
  while (rem >= 8 - ti) { rem -= 8 - ti; ++ti; }
  const int tj = ti + rem;
  const int tr = ti * 128, tc = tj * 128;
  const size_t MAT = (size_t)NN * NN;
  __shared__ unsigned short sm[32768];
  const int tid = threadIdx.x;
  const int wave = tid >> 6, lane = tid & 63;
  const int wm = (wave >> 1) * 64, wn = (wave & 1) * 64;
  const int q = lane >> 4, ln = lane & 15;
  const int rl = lane >> 3;
  const int gcol = ((lane & 7) ^ rl) << 3;
  const unsigned short* gp0;
  unsigned short* lb;
  if (wave == 0)      { gp0 = Uh + z * MAT + (size_t)tr * NN; lb = sm; }
  else if (wave == 1) { gp0 = Ul + z * MAT + (size_t)tr * NN; lb = sm + 8192; }
  else if (wave == 2) { gp0 = Wh + z * MAT + (size_t)tc * NN; lb = sm + 16384; }
  else                { gp0 = Wl + z * MAT + (size_t)tc * NN; lb = sm + 24576; }
  f32x4 acc[4][4];
  for (int i = 0; i < 4; ++i)
    for (int j = 0; j < 4; ++j) acc[i][j] = (f32x4){0.f, 0.f, 0.f, 0.f};
  const int swz = (ln & 7);
  for (int kc = 0; kc < NN; kc += 64) {
    __syncthreads();
    const unsigned short* gpk = gp0 + kc + gcol;
    for (int t = 0; t < 16; ++t)
      gload_lds16(gpk + (size_t)(t * 8 + rl) * NN, lb + t * 512);
    __syncthreads();
    for (int ks = 0; ks < 2; ++ks) {
      const int gq = ((ks * 4 + q) ^ swz) << 3;
      bf16x8 fah[4], fal[4], fbh[4], fbl[4];
      for (int i = 0; i < 4; ++i) {
        int off = (wm + i * 16 + ln) * 64 + gq;
        fah[i] = *(const bf16x8*)&sm[off];
        fal[i] = *(const bf16x8*)&sm[8192 + off];
      }
      for (int j = 0; j < 4; ++j) {
        int off = (wn + j * 16 + ln) * 64 + gq;
        fbh[j] = *(const bf16x8*)&sm[16384 + off];
        fbl[j] = *(const bf16x8*)&sm[24576 + off];
      }
      for (int i = 0; i < 4; ++i)
        for (int j = 0; j < 4; ++j) {
          acc[i][j] = __builtin_amdgcn_mfma_f32_16x16x32_bf16(fah[i], fbh[j], acc[i][j], 0, 0, 0);
          acc[i][j] = __builtin_amdgcn_mfma_f32_16x16x32_bf16(fah[i], fbl[j], acc[i][j], 0, 0, 0);
          acc[i][j] = __builtin_amdgcn_mfma_f32_16x16x32_bf16(fal[i], fbh[j], acc[i][j], 0, 0, 0);
        }
    }
  }
  // fused combine epilogue
  const unsigned short* wh = Wh + z * MAT;
  const unsigned short* wl = Wl + z * MAT;
  const unsigned short* uh = Uh + z * MAT;
  const unsigned short* ul = Ul + z * MAT;
  const float* dz = dcl + (z << 10);
  const float* iz = isq + (z << 10);
  float* Sb = S + z * MAT;
  const bool mirror = (ti != tj);
  for (int i = 0; i < 4; ++i) {
    int m0 = tr + wm + i * 16 + q * 4;
    float dm[4], im[4];
    for (int reg = 0; reg < 4; ++reg) {
      dm[reg] = dz[m0 + reg];
      im[reg] = iz[m0 + reg];
    }
    for (int j = 0; j < 4; ++j) {
      int n = tc + wn + j * 16 + ln;
      float dn = dz[n];
      float isn = iz[n];
      float sval[4];
      for (int reg = 0; reg < 4; ++reg) {
        size_t off = (size_t)(m0 + reg) * NN + n;
        float wv = bu2f(wh[off]) + bu2f(wl[off]);
        float uv = bu2f(uh[off]) + bu2f(ul[off]);
        float pf = 0.5f * (dm[reg] + dn) * im[reg] * isn;
        sval[reg] = pf * (wv + 0.8f * uv + 0.64f * acc[i][j][reg]);
        Sb[off] = sval[reg];
      }
      if (mirror) {
        *(float4*)&Sb[(size_t)n * NN + m0] =
            make_float4(sval[0], sval[1], sval[2], sval[3]);
      }
    }
  }
}

// thr[b] = min(diag) - mean(diag[:-1] - offdiag)
__global__ void __launch_bounds__(256) k_thr(const float* __restrict__ S,
                                             float* __restrict__ thr) {
  const int b = blockIdx.x;
  const float* Sb = S + (size_t)b * NN * NN;
  const int tid = threadIdx.x;
  float mn = 3.0e38f;
  float rsum = 0.f;
  for (int n = tid; n < NN; n += 256) {
    float d = Sb[(size_t)n * NN + n];
    mn = fminf(mn, d);
    if (n < NN - 1) rsum += d - Sb[(size_t)n * NN + n + 1];
  }
  __shared__ float tmp[4];
  float mtot = blockMinF(mn, tmp);
  float stot = blockSumF(rsum, tmp);
  if (tid == 0) thr[b] = mtot - stot / 1023.0f;
}

__global__ void __launch_bounds__(256) k_stats(const float* __restrict__ S,
                                               const float* __restrict__ thr,
                                               const float* __restrict__ wh1,
                                               const float* __restrict__ wh2,
                                               float* __restrict__ meanv,
                                               float* __restrict__ rstdv) {
  const int n = blockIdx.x;
  const int tid = threadIdx.x;
  double s1 = 0.0, s2 = 0.0;
  for (int b = 0; b < BB; ++b) {
    float t = thr[b];
    float w1 = wh1[b * NN + n];
    const float* Srow = S + ((size_t)b * NN + n) * NN;
    const float* w2p = wh2 + b * NN;
    for (int m = tid; m < NN; m += 256) {
      float e = w1 + w2p[m];
      e = (e > 0.f) ? e : 0.01f * e;
      float att = (Srow[m] > t) ? e : NEGV;
      s1 += (double)att;
      s2 += (double)att * (double)att;
    }
  }
  __shared__ double red[256];
  red[tid] = s1;
  __syncthreads();
  for (int s = 128; s > 0; s >>= 1) {
    if (tid < s) red[tid] += red[tid + s];
    __syncthreads();
  }
  double t1 = red[0];
  __syncthreads();
  red[tid] = s2;
  __syncthreads();
  for (int s = 128; s > 0; s >>= 1) {
    if (tid < s) red[tid] += red[tid + s];
    __syncthreads();
  }
  double t2 = red[0];
  if (tid == 0) {
    double mean = t1 / 8192.0;
    double var = t2 / 8192.0 - mean * mean;
    if (var < 0.0) var = 0.0;
    meanv[n] = (float)mean;
    rstdv[n] = (float)(1.0 / sqrt(var + 1e-5));
  }
}

__global__ void __launch_bounds__(256) k_out(const float* __restrict__ S,
                                             const float* __restrict__ thr,
                                             const float* __restrict__ wh1,
                                             const float* __restrict__ wh2,
                                             const float* __restrict__ meanv,
                                             const float* __restrict__ rstdv,
                                             const float* __restrict__ flag,
                                             void* outv) {
  const int bn = blockIdx.x;
  const int b = bn >> 10;
  const int n = bn & 1023;
  const int tid = threadIdx.x;
  const bool f32m = (flag[0] != 0.0f);
  const float t = thr[b];
  const float w1 = wh1[bn];
  const float* Srow = S + (size_t)bn * NN;
  const float* w2p = wh2 + b * NN;
  float v[4];
  float mx = -3.0e38f;
  for (int w = 0; w < 4; ++w) {
    int m = tid + (w << 8);
    float e = w1 + w2p[m];
    e = (e > 0.f) ? e : 0.01f * e;
    float att = (Srow[m] > t) ? e : NEGV;
    float vv = (att - meanv[n]) * rstdv[n];
    v[w] = vv;
    mx = fmaxf(mx, vv);
  }
  __shared__ float tmp[4];
  float gmx = blockMaxF(mx, tmp);
  float sum = 0.f;
  for (int w = 0; w < 4; ++w) {
    v[w] = __expf(v[w] - gmx);
    sum += v[w];
  }
  float gsum = blockSumF(sum, tmp);
  for (int w = 0; w < 4; ++w) {
    int m = tid + (w << 8);
    float val = v[w] / gsum;
    if (f32m) {
      ((float*)outv)[(size_t)bn * NN + m] = val;
    } else {
      ((bf16*)outv)[(size_t)bn * NN + m] = __float2bfloat16(val);
    }
  }
}

extern "C" void kernel_launch(void* const* d_in, const int* in_sizes, int n_in,
                              void* d_out, int out_size, void* d_ws,
                              size_t ws_size, hipStream_t stream) {
  float* ws = (float*)d_ws;

  float* sq = ws;              // 8192
  float* wh1 = ws + 8192;      // 8192
  float* wh2 = ws + 16384;     // 8192
  float* thr = ws + 24576;     // 8
  float* meanv = ws + 24608;   // 1024
  float* rstdv = ws + 25632;   // 1024
  float* flag = ws + 26656;    // 8
  float* isq = ws + 26664;     // 8192 (fits before 40960)
  float* rsum = ws + 40960;    // 8192
  float* dcl = ws + 49152;     // 8192

  unsigned short* Hh = (unsigned short*)(ws + 65536);   // 524288 ushorts
  unsigned short* Hl = (unsigned short*)(ws + 327680);  // 524288 ushorts

  unsigned short* Wh = (unsigned short*)(ws + 589824);
  unsigned short* Wl = (unsigned short*)(ws + 4784128);
  unsigned short* Uh = (unsigned short*)(ws + 17367040);
  unsigned short* Ul = (unsigned short*)(ws + 21561344);
  float* Sf = ws + 25755648;  // 8388608 floats (final S)
  const size_t needed_fast = (25755648ull + 8388608ull) * 4ull;

  if (ws_size < needed_fast) {
    k_fill<<<dim3(2048), 256, 0, stream>>>((unsigned short*)d_out, out_size,
                                           (unsigned short)0xBF80);
    return;
  }

  k_detect<<<dim3(1), 256, 0, stream>>>((const unsigned short*)d_in[0], flag);
  k_h<<<dim3(BB * NN), 64, 0, stream>>>(d_in[0], d_in[1], d_in[2], flag, Hh, Hl,
                                        sq, wh1, wh2);
  k_zero<<<dim3(32), 256, 0, stream>>>(rsum, BB * NN);
  k_g0<<<dim3(512), 256, 0, stream>>>(Hh, Hl, sq, rsum);
  k_scal<<<dim3(32), 256, 0, stream>>>(rsum, dcl, isq);
  k_gw<<<dim3(512), 256, 0, stream>>>(Hh, Hl, sq, isq, Wh, Wl);
  k_mm1<<<dim3(288), 256, 0, stream>>>(Wh, Wl, Uh, Ul);
  k_mm2<<<dim3(288), 256, 0, stream>>>(Uh, Ul, Wh, Wl, dcl, isq, Sf);
  k_thr<<<dim3(BB), 256, 0, stream>>>(Sf, thr);
  k_stats<<<dim3(NN), 256, 0, stream>>>(Sf, thr, wh1, wh2, meanv, rstdv);
  k_out<<<dim3(BB * NN), 256, 0, stream>>>(Sf, thr, wh1, wh2, meanv, rstdv,
                                           flag, d_out);
}